// Round 3
// baseline (529.208 us; speedup 1.0000x reference)
//
#include <hip/hip_runtime.h>
#include <hip/hip_bf16.h>

#define NN 20000
#define EE 320000
#define LGN 4

typedef unsigned short u16;
typedef short bf16x8 __attribute__((ext_vector_type(8)));
typedef unsigned short u16x8 __attribute__((ext_vector_type(8)));
typedef float f32x4 __attribute__((ext_vector_type(4)));

__device__ __forceinline__ float bf2f(u16 v) {
    unsigned int u = ((unsigned int)v) << 16;
    float f; __builtin_memcpy(&f, &u, 4); return f;
}
__device__ __forceinline__ u16 f2bf(float f) {
    __hip_bfloat16 h = __float2bfloat16(f);
    u16 u; __builtin_memcpy(&u, &h, 2); return u;
}

// ---- pass 1: degree (by source), col histogram, ew copy-out ----
__global__ __launch_bounds__(256) void k_edge1(const int* __restrict__ ei,
                                               const float* __restrict__ ew,
                                               float* __restrict__ deg,
                                               int* __restrict__ counts,
                                               float* __restrict__ out_ew) {
    int e = blockIdx.x * 256 + threadIdx.x;
    if (e >= EE) return;
    int r = ei[e];
    float w = ew[e];
    atomicAdd(&deg[r], w);
    atomicAdd(&counts[ei[EE + e]], 1);
    out_ew[e] = w;
}

// ---- exclusive scan of col histogram (single block) ----
__global__ __launch_bounds__(1024) void k_scan(const int* __restrict__ counts,
                                               int* __restrict__ offs) {
    __shared__ int part[1024];
    int t = threadIdx.x;
    const int C = (NN + 1023) / 1024;  // 20
    int lo = t * C, hi = min(lo + C, NN);
    int s = 0;
    for (int i = lo; i < hi; i++) s += counts[i];
    part[t] = s;
    __syncthreads();
    for (int off = 1; off < 1024; off <<= 1) {
        int add = (t >= off) ? part[t - off] : 0;
        __syncthreads();
        part[t] += add;
        __syncthreads();
    }
    int base = part[t] - s;
    for (int i = lo; i < hi; i++) { offs[i] = base; base += counts[i]; }
    if (t == 1023) offs[NN] = part[1023];
}

// ---- pass 2: compute norm (rsqrt folded in, bit-identical to separate
// k_rsqrt), scatter (row, norm) int2 into CSR slots ----
__global__ __launch_bounds__(256) void k_scatter(const int* __restrict__ ei,
                                                 const float* __restrict__ ew,
                                                 const float* __restrict__ deg,
                                                 const int* __restrict__ offs,
                                                 int* __restrict__ cursor,
                                                 int2* __restrict__ nbrs) {
    int e = blockIdx.x * 256 + threadIdx.x;
    if (e >= EE) return;
    int r = ei[e], c = ei[EE + e];
    float dr = deg[r], dc = deg[c];
    float ir = (dr > 0.f) ? rsqrtf(dr) : 0.f;
    float ic = (dc > 0.f) ? rsqrtf(dc) : 0.f;
    float nm = -(ir * ew[e] * ic);
    int pidx = offs[c] + atomicAdd(&cursor[c], 1);
    nbrs[pidx] = make_int2(r, __float_as_int(nm));
}

// ---- f32 -> bf16 cast (no transpose) ----
__global__ __launch_bounds__(256) void k_cast(const float* __restrict__ src,
                                              u16* __restrict__ dst, int n) {
    int i = blockIdx.x * 256 + threadIdx.x;
    if (i < n) dst[i] = f2bf(src[i]);
}

// ---- f32 [K][256] -> bf16 fragment-tiled Bf layout ----
// Bf: per (k-step s of 32, n-frag f of 16 cols) one 1KB chunk; lane l owns
// 16B = B[col=f*16+(l&15)][k=s*32+(l>>4)*8 .. +7]. GEMM waves then load B
// frags straight to VGPRs with fully-coalesced global_load_dwordx4 -- no LDS.
// grid.y selects a weight set (stride K*256 in both src and dst).
__global__ __launch_bounds__(256) void k_castB(const float* __restrict__ src,
                                               u16* __restrict__ dst, int K) {
    src += (size_t)blockIdx.y * K * 256;
    dst += (size_t)blockIdx.y * K * 256;
    int tid = blockIdx.x * 256 + threadIdx.x;
    if (tid >= (K >> 5) * 1024) return;
    int l = tid & 63, f = (tid >> 6) & 15, s = tid >> 10;
    int col = f * 16 + (l & 15);
    int kb = s * 32 + ((l >> 4) << 3);
    u16 tmp[8];
#pragma unroll
    for (int j = 0; j < 8; j++) tmp[j] = f2bf(src[(size_t)(kb + j) * 256 + col]);
    *(uint4*)(dst + (size_t)tid * 8) = *(uint4*)tmp;
}

// ---- fold BN affine: s = gamma*rsqrt(var+eps), t = beta - mean*s ----
__global__ __launch_bounds__(256) void k_foldbn(const float* __restrict__ g,
                                                const float* __restrict__ be,
                                                const float* __restrict__ mn,
                                                const float* __restrict__ vr,
                                                float* __restrict__ sc,
                                                float* __restrict__ sh) {
    int t = threadIdx.x;
    if (t < 256) {
        float s = g[t] * rsqrtf(vr[t] + 1e-5f);
        sc[t] = s;
        sh[t] = be[t] - mn[t] * s;
    }
}

// ---- CSR SpMM: one WAVE per node, no LDS, no barriers ----
// R14: half-wave pairing -- lanes 0-31 handle neighbor i+2j, lanes 32-63
// neighbor i+2j+1, each lane a 16B dwordx4 (cols 8*(l&31)..+7). Same bytes
// and same ceil-8 gather granularity as before (second 4-pair sub-batch is
// wave-uniform gated), but HALF the VMEM instructions at the 16B/lane
// coalescing sweet spot. Halves folded with 8 shfl_xor(32) at the end.
__global__ __launch_bounds__(256) void k_prop(const u16* __restrict__ x, int ldx,
                                              const u16* __restrict__ xsub, int ldsub,
                                              int dotx2,
                                              u16* __restrict__ out, int ldo,
                                              const int* __restrict__ offs,
                                              const int2* __restrict__ nbrs) {
    int c = __builtin_amdgcn_readfirstlane(blockIdx.x * 4 + (threadIdx.x >> 6));
    int l = threadIdx.x & 63;
    int hf = l >> 5;   // which neighbor of the pair
    int cl = l & 31;   // cols 8*cl .. 8*cl+7
    int s = offs[c], e = offs[c + 1];
    float acc0 = 0.f, acc1 = 0.f, acc2 = 0.f, acc3 = 0.f;
    float acc4 = 0.f, acc5 = 0.f, acc6 = 0.f, acc7 = 0.f;
    for (int i = s; i < e; i += 16) {
        int2 mm[8];
        u16x8 xv[8];
#pragma unroll
        for (int j = 0; j < 4; j++) mm[j] = nbrs[i + 2 * j + hf];
#pragma unroll
        for (int j = 0; j < 4; j++)
            xv[j] = *(const u16x8*)(x + (size_t)mm[j].x * ldx + cl * 8);
        bool more = (i + 8 < e);  // wave-uniform
        if (more) {
#pragma unroll
            for (int j = 4; j < 8; j++) mm[j] = nbrs[i + 2 * j + hf];
#pragma unroll
            for (int j = 4; j < 8; j++)
                xv[j] = *(const u16x8*)(x + (size_t)mm[j].x * ldx + cl * 8);
        }
#pragma unroll
        for (int j = 0; j < 4; j++) {
            float w = (i + 2 * j + hf < e) ? __int_as_float(mm[j].y) : 0.f;
            acc0 += w * bf2f(xv[j][0]);
            acc1 += w * bf2f(xv[j][1]);
            acc2 += w * bf2f(xv[j][2]);
            acc3 += w * bf2f(xv[j][3]);
            acc4 += w * bf2f(xv[j][4]);
            acc5 += w * bf2f(xv[j][5]);
            acc6 += w * bf2f(xv[j][6]);
            acc7 += w * bf2f(xv[j][7]);
        }
        if (more) {
#pragma unroll
            for (int j = 4; j < 8; j++) {
                float w = (i + 2 * j + hf < e) ? __int_as_float(mm[j].y) : 0.f;
                acc0 += w * bf2f(xv[j][0]);
                acc1 += w * bf2f(xv[j][1]);
                acc2 += w * bf2f(xv[j][2]);
                acc3 += w * bf2f(xv[j][3]);
                acc4 += w * bf2f(xv[j][4]);
                acc5 += w * bf2f(xv[j][5]);
                acc6 += w * bf2f(xv[j][6]);
                acc7 += w * bf2f(xv[j][7]);
            }
        }
    }
    // fold the two half-wave partials
    acc0 += __shfl_xor(acc0, 32, 64);
    acc1 += __shfl_xor(acc1, 32, 64);
    acc2 += __shfl_xor(acc2, 32, 64);
    acc3 += __shfl_xor(acc3, 32, 64);
    acc4 += __shfl_xor(acc4, 32, 64);
    acc5 += __shfl_xor(acc5, 32, 64);
    acc6 += __shfl_xor(acc6, 32, 64);
    acc7 += __shfl_xor(acc7, 32, 64);
    if (dotx2) {
        u16x8 xs = *(const u16x8*)(xsub + (size_t)c * ldsub + cl * 8);
        acc0 = 2.f * acc0 - bf2f(xs[0]);
        acc1 = 2.f * acc1 - bf2f(xs[1]);
        acc2 = 2.f * acc2 - bf2f(xs[2]);
        acc3 = 2.f * acc3 - bf2f(xs[3]);
        acc4 = 2.f * acc4 - bf2f(xs[4]);
        acc5 = 2.f * acc5 - bf2f(xs[5]);
        acc6 = 2.f * acc6 - bf2f(xs[6]);
        acc7 = 2.f * acc7 - bf2f(xs[7]);
    }
    if (hf == 0) {
        u16 o[8];
        o[0] = f2bf(acc0); o[1] = f2bf(acc1); o[2] = f2bf(acc2); o[3] = f2bf(acc3);
        o[4] = f2bf(acc4); o[5] = f2bf(acc5); o[6] = f2bf(acc6); o[7] = f2bf(acc7);
        *(uint4*)(out + (size_t)c * ldo + cl * 8) = *(uint4*)o;
    }
}

// ---- bf16 MFMA GEMM: tile M=64 x N=256, NO LDS / NO BARRIERS in K-loop ----
// R14: R1's depth-3 pipeline was a null (scheduling wasn't the bottleneck);
// R2's B-bypass (-16 gll16/step) gave -30%. Conclusion: cost tracks the
// gll16+barrier structure itself. A has no cross-block reuse and its 4-way
// cross-wave reuse is absorbed by L1 (A step footprint 4KB << 32KB), so each
// wave now loads its own A frags straight to VGPRs. Chunk-major loop with
// unroll-8 inner; zero barriers, zero inline asm -- compiler is free to
// software-pipeline the plain loads under the MFMAs.
// mode 0: relu -> bf16 via per-wave LDS transpose (LDS untouched by K-loop,
// no barrier needed). mode 1: +bias, relu, BN affine, @w2 + b2 -> LDS
// cross-wave reduce (single barrier), plain store.
__global__ __launch_bounds__(256, 3) void k_gemm(
    const u16* __restrict__ A0, const u16* __restrict__ A1,
    const u16* __restrict__ A2, const u16* __restrict__ A3,
    int lda0, int lda1, int lda2, int lda3,
    int K, const u16* __restrict__ Bf,
    int mode,
    u16* __restrict__ outb, int ldob,
    const float* __restrict__ bias, const float* __restrict__ sc,
    const float* __restrict__ sh,
    const float* __restrict__ w2, const float* __restrict__ b2,
    float* __restrict__ outlog) {
    __shared__ __align__(16) u16 lds[18432];  // 36 KB, epilogue only
    int t = threadIdx.x;
    int wv = t >> 6, l = t & 63;
    int q = l >> 4, l16 = l & 15;
    int m0 = blockIdx.x * 64;
    int n0 = wv * 64;

    f32x4 acc[4][4] = {};  // [mh][nt]

    int rmh[4];
#pragma unroll
    for (int mh = 0; mh < 4; mh++) rmh[mh] = min(m0 + mh * 16 + l16, NN - 1);

    const u16* bfw = Bf + (size_t)(wv * 4) * 512 + (size_t)l * 8;
    const int nch = K >> 8;  // 3 or 4 chunks of 8 k-steps
    for (int ch = 0; ch < nch; ch++) {
        const u16* ap; int la;
        if (ch == 0) { ap = A0; la = lda0; }
        else if (ch == 1) { ap = A1; la = lda1; }
        else if (ch == 2) { ap = A2; la = lda2; }
        else { ap = A3; la = lda3; }
        const u16* aw0 = ap + (size_t)rmh[0] * la + q * 8;
        const u16* aw1 = ap + (size_t)rmh[1] * la + q * 8;
        const u16* aw2 = ap + (size_t)rmh[2] * la + q * 8;
        const u16* aw3 = ap + (size_t)rmh[3] * la + q * 8;
        const u16* bch = bfw + (size_t)ch * 8 * 8192;
#pragma unroll
        for (int ss = 0; ss < 8; ss++) {
            bf16x8 a0 = *(const bf16x8*)(aw0 + ss * 32);
            bf16x8 a1 = *(const bf16x8*)(aw1 + ss * 32);
            bf16x8 a2 = *(const bf16x8*)(aw2 + ss * 32);
            bf16x8 a3 = *(const bf16x8*)(aw3 + ss * 32);
            bf16x8 b0 = *(const bf16x8*)(bch + ss * 8192 + 0 * 512);
            bf16x8 b1 = *(const bf16x8*)(bch + ss * 8192 + 1 * 512);
            bf16x8 b2v = *(const bf16x8*)(bch + ss * 8192 + 2 * 512);
            bf16x8 b3 = *(const bf16x8*)(bch + ss * 8192 + 3 * 512);
            acc[0][0] = __builtin_amdgcn_mfma_f32_16x16x32_bf16(a0, b0, acc[0][0], 0, 0, 0);
            acc[0][1] = __builtin_amdgcn_mfma_f32_16x16x32_bf16(a0, b1, acc[0][1], 0, 0, 0);
            acc[0][2] = __builtin_amdgcn_mfma_f32_16x16x32_bf16(a0, b2v, acc[0][2], 0, 0, 0);
            acc[0][3] = __builtin_amdgcn_mfma_f32_16x16x32_bf16(a0, b3, acc[0][3], 0, 0, 0);
            acc[1][0] = __builtin_amdgcn_mfma_f32_16x16x32_bf16(a1, b0, acc[1][0], 0, 0, 0);
            acc[1][1] = __builtin_amdgcn_mfma_f32_16x16x32_bf16(a1, b1, acc[1][1], 0, 0, 0);
            acc[1][2] = __builtin_amdgcn_mfma_f32_16x16x32_bf16(a1, b2v, acc[1][2], 0, 0, 0);
            acc[1][3] = __builtin_amdgcn_mfma_f32_16x16x32_bf16(a1, b3, acc[1][3], 0, 0, 0);
            acc[2][0] = __builtin_amdgcn_mfma_f32_16x16x32_bf16(a2, b0, acc[2][0], 0, 0, 0);
            acc[2][1] = __builtin_amdgcn_mfma_f32_16x16x32_bf16(a2, b1, acc[2][1], 0, 0, 0);
            acc[2][2] = __builtin_amdgcn_mfma_f32_16x16x32_bf16(a2, b2v, acc[2][2], 0, 0, 0);
            acc[2][3] = __builtin_amdgcn_mfma_f32_16x16x32_bf16(a2, b3, acc[2][3], 0, 0, 0);
            acc[3][0] = __builtin_amdgcn_mfma_f32_16x16x32_bf16(a3, b0, acc[3][0], 0, 0, 0);
            acc[3][1] = __builtin_amdgcn_mfma_f32_16x16x32_bf16(a3, b1, acc[3][1], 0, 0, 0);
            acc[3][2] = __builtin_amdgcn_mfma_f32_16x16x32_bf16(a3, b2v, acc[3][2], 0, 0, 0);
            acc[3][3] = __builtin_amdgcn_mfma_f32_16x16x32_bf16(a3, b3, acc[3][3], 0, 0, 0);
        }
    }

    if (mode == 0) {
        u16* Cs = lds + wv * 4608;  // per-wave [64][72] (private: no barrier)
#pragma unroll
        for (int mh = 0; mh < 4; mh++)
#pragma unroll
            for (int j = 0; j < 4; j++)
#pragma unroll
                for (int i = 0; i < 4; i++) {
                    float v = acc[mh][j][i];
                    v = v > 0.f ? v : 0.f;
                    Cs[(mh * 16 + q * 4 + i) * 72 + j * 16 + l16] = f2bf(v);
                }
        // same-wave ds_write->ds_read ordered via lgkmcnt
#pragma unroll
        for (int j = 0; j < 8; j++) {
            int f = j * 64 + l;
            int r = f >> 3, cc = (f & 7) * 8;
            uint4 cv = *(const uint4*)&Cs[r * 72 + cc];
            int row = m0 + r;
            if (row < NN) *(uint4*)(outb + (size_t)row * ldob + n0 + cc) = cv;
        }
    } else {
        float bi[4], s4[4], h4[4], wa[4], wb[4];
#pragma unroll
        for (int j = 0; j < 4; j++) {
            int col = n0 + j * 16 + l16;
            bi[j] = bias[col];
            s4[j] = sc[col];
            h4[j] = sh[col];
            wa[j] = w2[2 * col];
            wb[j] = w2[2 * col + 1];
        }
        float* red = (float*)lds;  // [4 waves][64 rows][2]
#pragma unroll
        for (int mh = 0; mh < 4; mh++)
#pragma unroll
            for (int i = 0; i < 4; i++) {
                float p0 = 0.f, p1 = 0.f;
#pragma unroll
                for (int j = 0; j < 4; j++) {
                    float v = acc[mh][j][i] + bi[j];
                    v = v > 0.f ? v : 0.f;
                    v = v * s4[j] + h4[j];
                    p0 += v * wa[j];
                    p1 += v * wb[j];
                }
#pragma unroll
                for (int off = 1; off < 16; off <<= 1) {
                    p0 += __shfl_xor(p0, off, 64);
                    p1 += __shfl_xor(p1, off, 64);
                }
                if (l16 == 0) {
                    int rl = mh * 16 + q * 4 + i;
                    red[(wv * 64 + rl) * 2 + 0] = p0;
                    red[(wv * 64 + rl) * 2 + 1] = p1;
                }
            }
        __syncthreads();
        if (t < 128) {
            int rl = t >> 1, cp = t & 1;
            float v = red[(0 * 64 + rl) * 2 + cp] + red[(1 * 64 + rl) * 2 + cp] +
                      red[(2 * 64 + rl) * 2 + cp] + red[(3 * 64 + rl) * 2 + cp];
            int row = m0 + rl;
            if (row < NN) outlog[(size_t)row * 2 + cp] = v + b2[cp];
        }
    }
}

extern "C" void kernel_launch(void* const* d_in, const int* in_sizes, int n_in,
                              void* d_out, int out_size, void* d_ws, size_t ws_size,
                              hipStream_t stream) {
    const float* features = (const float*)d_in[0];
    const int* ei = (const int*)d_in[1];
    // d_in[2] = edgenet_input (bypassed by edge_weight_override)
    const float* ew = (const float*)d_in[3];
    const float* cheb_w = (const float*)d_in[4];
    const float* w1 = (const float*)d_in[5];
    const float* b1 = (const float*)d_in[6];
    const float* g = (const float*)d_in[7];
    const float* be = (const float*)d_in[8];
    const float* mn = (const float*)d_in[9];
    const float* vr = (const float*)d_in[10];
    const float* w2 = (const float*)d_in[11];
    const float* b2 = (const float*)d_in[12];
    float* out = (float*)d_out;  // [NN*2] logits, then [EE] ew

    char* p = (char*)d_ws;
    auto alloc = [&](size_t bytes) -> char* {
        char* r = p;
        p += (bytes + 255) & ~(size_t)255;
        return r;
    };
    float* deg = (float*)alloc((size_t)NN * 4);
    int* counts = (int*)alloc((size_t)(NN + 1) * 4);
    int* cursor = (int*)alloc((size_t)NN * 4);
    size_t zero_bytes = (size_t)(p - (char*)deg);
    int* offs = (int*)alloc((size_t)(NN + 1) * 4);
    int2* nbrs = (int2*)alloc((size_t)(EE + 16) * 8);
    u16* xb = (u16*)alloc((size_t)NN * 256 * 2);
    u16* tx1 = (u16*)alloc((size_t)NN * 256 * 2);
    u16* tx2 = (u16*)alloc((size_t)NN * 256 * 2);
    u16* jk = (u16*)alloc((size_t)NN * 1024 * 2);
    u16* chebT = (u16*)alloc((size_t)LGN * 3 * 256 * 256 * 2);  // per layer frag-tiled [768K]
    u16* w1T = (u16*)alloc((size_t)1024 * 256 * 2);             // frag-tiled [1024K]
    float* sc = (float*)alloc(256 * 4);
    float* sh = (float*)alloc(256 * 4);

    hipMemsetAsync(deg, 0, zero_bytes, stream);
    hipMemsetAsync(nbrs + EE, 0, 16 * sizeof(int2), stream);  // safe overrun pad
    k_edge1<<<(EE + 255) / 256, 256, 0, stream>>>(ei, ew, deg, counts, out + (size_t)NN * 2);
    k_scan<<<1, 1024, 0, stream>>>(counts, offs);
    k_scatter<<<(EE + 255) / 256, 256, 0, stream>>>(ei, ew, deg, offs, cursor, nbrs);
    k_cast<<<((NN * 256) + 255) / 256, 256, 0, stream>>>(features, xb, NN * 256);
    k_castB<<<dim3(96, LGN), 256, 0, stream>>>(cheb_w, chebT, 768);
    k_castB<<<dim3(128, 1), 256, 0, stream>>>(w1, w1T, 1024);
    k_foldbn<<<1, 256, 0, stream>>>(g, be, mn, vr, sc, sh);

    const int gg = (NN + 63) / 64;  // 313 blocks (tile M=64 x N=256)
    for (int i = 0; i < LGN; i++) {
        const u16* x = (i == 0) ? xb : (jk + (size_t)(i - 1) * 256);
        int ldx = (i == 0) ? 256 : 1024;
        k_prop<<<NN / 4, 256, 0, stream>>>(x, ldx, (const u16*)nullptr, 0, 0, tx1, 256, offs,
                                           nbrs);
        k_prop<<<NN / 4, 256, 0, stream>>>(tx1, 256, x, ldx, 1, tx2, 256, offs, nbrs);
        k_gemm<<<gg, 256, 0, stream>>>(
            x, tx1, tx2, (const u16*)nullptr, ldx, 256, 256, 0, 768,
            chebT + (size_t)i * 256 * 768, 0, jk + (size_t)i * 256, 1024, (const float*)nullptr,
            (const float*)nullptr, (const float*)nullptr, (const float*)nullptr,
            (const float*)nullptr, (float*)nullptr);
    }
    k_gemm<<<gg, 256, 0, stream>>>(jk, jk + 256, jk + 512, jk + 768, 1024, 1024, 1024, 1024,
                                   1024, w1T, 1, (u16*)nullptr, 0, b1, sc, sh, w2, b2, out);
}

// Round 4
// 528.361 us; speedup vs baseline: 1.0016x; 1.0016x over previous
//
#include <hip/hip_runtime.h>
#include <hip/hip_bf16.h>

#define NN 20000
#define EE 320000
#define LGN 4

typedef unsigned short u16;
typedef short bf16x8 __attribute__((ext_vector_type(8)));
typedef unsigned short u16x8 __attribute__((ext_vector_type(8)));
typedef float f32x4 __attribute__((ext_vector_type(4)));

__device__ __forceinline__ float bf2f(u16 v) {
    unsigned int u = ((unsigned int)v) << 16;
    float f; __builtin_memcpy(&f, &u, 4); return f;
}
__device__ __forceinline__ u16 f2bf(float f) {
    __hip_bfloat16 h = __float2bfloat16(f);
    u16 u; __builtin_memcpy(&u, &h, 2); return u;
}

// async global->LDS, 16B per lane, LDS dest = wave-uniform base + lane*16
__device__ __forceinline__ void gll16(const void* g, void* l) {
    __builtin_amdgcn_global_load_lds(
        (const __attribute__((address_space(1))) unsigned int*)g,
        (__attribute__((address_space(3))) unsigned int*)l, 16, 0, 0);
}

// ---- pass 1: degree (by source), col histogram, ew copy-out ----
__global__ __launch_bounds__(256) void k_edge1(const int* __restrict__ ei,
                                               const float* __restrict__ ew,
                                               float* __restrict__ deg,
                                               int* __restrict__ counts,
                                               float* __restrict__ out_ew) {
    int e = blockIdx.x * 256 + threadIdx.x;
    if (e >= EE) return;
    int r = ei[e];
    float w = ew[e];
    atomicAdd(&deg[r], w);
    atomicAdd(&counts[ei[EE + e]], 1);
    out_ew[e] = w;
}

// ---- exclusive scan of col histogram (single block) ----
__global__ __launch_bounds__(1024) void k_scan(const int* __restrict__ counts,
                                               int* __restrict__ offs) {
    __shared__ int part[1024];
    int t = threadIdx.x;
    const int C = (NN + 1023) / 1024;  // 20
    int lo = t * C, hi = min(lo + C, NN);
    int s = 0;
    for (int i = lo; i < hi; i++) s += counts[i];
    part[t] = s;
    __syncthreads();
    for (int off = 1; off < 1024; off <<= 1) {
        int add = (t >= off) ? part[t - off] : 0;
        __syncthreads();
        part[t] += add;
        __syncthreads();
    }
    int base = part[t] - s;
    for (int i = lo; i < hi; i++) { offs[i] = base; base += counts[i]; }
    if (t == 1023) offs[NN] = part[1023];
}

// ---- pass 2: compute norm (rsqrt folded in, bit-identical to separate
// k_rsqrt), scatter (row, norm) int2 into CSR slots ----
__global__ __launch_bounds__(256) void k_scatter(const int* __restrict__ ei,
                                                 const float* __restrict__ ew,
                                                 const float* __restrict__ deg,
                                                 const int* __restrict__ offs,
                                                 int* __restrict__ cursor,
                                                 int2* __restrict__ nbrs) {
    int e = blockIdx.x * 256 + threadIdx.x;
    if (e >= EE) return;
    int r = ei[e], c = ei[EE + e];
    float dr = deg[r], dc = deg[c];
    float ir = (dr > 0.f) ? rsqrtf(dr) : 0.f;
    float ic = (dc > 0.f) ? rsqrtf(dc) : 0.f;
    float nm = -(ir * ew[e] * ic);
    int pidx = offs[c] + atomicAdd(&cursor[c], 1);
    nbrs[pidx] = make_int2(r, __float_as_int(nm));
}

// ---- f32 -> bf16 cast (no transpose) ----
__global__ __launch_bounds__(256) void k_cast(const float* __restrict__ src,
                                              u16* __restrict__ dst, int n) {
    int i = blockIdx.x * 256 + threadIdx.x;
    if (i < n) dst[i] = f2bf(src[i]);
}

// ---- f32 [K][256] -> bf16 fragment-tiled Bf layout ----
// Bf: per (k-step s of 32, n-frag f of 16 cols) one 1KB chunk; lane l owns
// 16B = B[col=f*16+(l&15)][k=s*32+(l>>4)*8 .. +7]. GEMM waves then load B
// frags straight to VGPRs with fully-coalesced global_load_dwordx4 -- no LDS.
// grid.y selects a weight set (stride K*256 in both src and dst).
__global__ __launch_bounds__(256) void k_castB(const float* __restrict__ src,
                                               u16* __restrict__ dst, int K) {
    src += (size_t)blockIdx.y * K * 256;
    dst += (size_t)blockIdx.y * K * 256;
    int tid = blockIdx.x * 256 + threadIdx.x;
    if (tid >= (K >> 5) * 1024) return;
    int l = tid & 63, f = (tid >> 6) & 15, s = tid >> 10;
    int col = f * 16 + (l & 15);
    int kb = s * 32 + ((l >> 4) << 3);
    u16 tmp[8];
#pragma unroll
    for (int j = 0; j < 8; j++) tmp[j] = f2bf(src[(size_t)(kb + j) * 256 + col]);
    *(uint4*)(dst + (size_t)tid * 8) = *(uint4*)tmp;
}

// ---- fold BN affine: s = gamma*rsqrt(var+eps), t = beta - mean*s ----
__global__ __launch_bounds__(256) void k_foldbn(const float* __restrict__ g,
                                                const float* __restrict__ be,
                                                const float* __restrict__ mn,
                                                const float* __restrict__ vr,
                                                float* __restrict__ sc,
                                                float* __restrict__ sh) {
    int t = threadIdx.x;
    if (t < 256) {
        float s = g[t] * rsqrtf(vr[t] + 1e-5f);
        sc[t] = s;
        sh[t] = be[t] - mn[t] * s;
    }
}

// ---- CSR SpMM, R15: XCD-sliced columns for L2-resident gathers ----
// Working set of x = 10 MB > 4 MiB XCD-L2 -> 164 MB of row-gathers/dispatch
// were served by L3 (slow). Split the 256 cols into 4 slices of 64; slice =
// blockIdx&3 so the %8 XCD round-robin pins slice s to XCDs {s, s+4}:
// per-XCD working set 2.5 MB -> L2-resident. Wave = 1 node: 8 lanes per
// neighbor x 16B = one 128B row-segment; 8 neighbors per gather instruction,
// 2 gathers in flight (wave-uniform gated); butterfly-fold over lane-groups.
__global__ __launch_bounds__(256) void k_prop(const u16* __restrict__ x, int ldx,
                                              const u16* __restrict__ xsub, int ldsub,
                                              int dotx2,
                                              u16* __restrict__ out, int ldo,
                                              const int* __restrict__ offs,
                                              const int2* __restrict__ nbrs) {
    int sl = blockIdx.x & 3;  // column slice (XCD-pinned via %8 round-robin)
    int c = __builtin_amdgcn_readfirstlane((blockIdx.x >> 2) * 4 + (threadIdx.x >> 6));
    int l = threadIdx.x & 63;
    int g = l >> 3;              // neighbor lane-group 0..7
    int o = l & 7;               // 16B chunk within the 128B row segment
    int cb = sl * 64 + o * 8;    // first col this lane covers
    int s = offs[c], e = offs[c + 1];
    float a0 = 0.f, a1 = 0.f, a2 = 0.f, a3 = 0.f;
    float a4 = 0.f, a5 = 0.f, a6 = 0.f, a7 = 0.f;
    for (int i = s; i < e; i += 16) {
        int2 m0 = nbrs[i + g];       // 8-lane broadcast groups (pad covers +15)
        int2 m1 = nbrs[i + 8 + g];
        u16x8 x0 = *(const u16x8*)(x + (size_t)m0.x * ldx + cb);
        bool more = (i + 8 < e);     // wave-uniform
        u16x8 x1 = x0;
        if (more) x1 = *(const u16x8*)(x + (size_t)m1.x * ldx + cb);
        float w0 = (i + g < e) ? __int_as_float(m0.y) : 0.f;
        a0 += w0 * bf2f(x0[0]);
        a1 += w0 * bf2f(x0[1]);
        a2 += w0 * bf2f(x0[2]);
        a3 += w0 * bf2f(x0[3]);
        a4 += w0 * bf2f(x0[4]);
        a5 += w0 * bf2f(x0[5]);
        a6 += w0 * bf2f(x0[6]);
        a7 += w0 * bf2f(x0[7]);
        if (more) {
            float w1 = (i + 8 + g < e) ? __int_as_float(m1.y) : 0.f;
            a0 += w1 * bf2f(x1[0]);
            a1 += w1 * bf2f(x1[1]);
            a2 += w1 * bf2f(x1[2]);
            a3 += w1 * bf2f(x1[3]);
            a4 += w1 * bf2f(x1[4]);
            a5 += w1 * bf2f(x1[5]);
            a6 += w1 * bf2f(x1[6]);
            a7 += w1 * bf2f(x1[7]);
        }
    }
    // butterfly-fold across the 8 neighbor lane-groups (xor bits 3,4,5)
#pragma unroll
    for (int off = 8; off < 64; off <<= 1) {
        a0 += __shfl_xor(a0, off, 64);
        a1 += __shfl_xor(a1, off, 64);
        a2 += __shfl_xor(a2, off, 64);
        a3 += __shfl_xor(a3, off, 64);
        a4 += __shfl_xor(a4, off, 64);
        a5 += __shfl_xor(a5, off, 64);
        a6 += __shfl_xor(a6, off, 64);
        a7 += __shfl_xor(a7, off, 64);
    }
    if (dotx2) {
        u16x8 xs = *(const u16x8*)(xsub + (size_t)c * ldsub + cb);
        a0 = 2.f * a0 - bf2f(xs[0]);
        a1 = 2.f * a1 - bf2f(xs[1]);
        a2 = 2.f * a2 - bf2f(xs[2]);
        a3 = 2.f * a3 - bf2f(xs[3]);
        a4 = 2.f * a4 - bf2f(xs[4]);
        a5 = 2.f * a5 - bf2f(xs[5]);
        a6 = 2.f * a6 - bf2f(xs[6]);
        a7 = 2.f * a7 - bf2f(xs[7]);
    }
    if (g == 0) {  // lanes 0..7 store 8 x 16B = the 128B slice segment
        u16 ov[8];
        ov[0] = f2bf(a0); ov[1] = f2bf(a1); ov[2] = f2bf(a2); ov[3] = f2bf(a3);
        ov[4] = f2bf(a4); ov[5] = f2bf(a5); ov[6] = f2bf(a6); ov[7] = f2bf(a7);
        *(uint4*)(out + (size_t)c * ldo + cb) = *(uint4*)ov;
    }
}

// ---- bf16 MFMA GEMM: tile M=64 x N=256 (R2 measured-best form). ----
// B frags are wave-PRIVATE -> register ping-pong from frag-tiled Bf (no LDS).
// Only A (shared by all 4 waves) is staged: 1 gll16 per wave per step,
// quad-buffered depth-3 with counted vmcnt. LDS 36 KB, 3 blocks/CU.
__global__ __launch_bounds__(256, 3) void k_gemm(
    const u16* __restrict__ A0, const u16* __restrict__ A1,
    const u16* __restrict__ A2, const u16* __restrict__ A3,
    int lda0, int lda1, int lda2, int lda3,
    int K, const u16* __restrict__ Bf,
    int mode,
    u16* __restrict__ outb, int ldob,
    const float* __restrict__ bias, const float* __restrict__ sc,
    const float* __restrict__ sh,
    const float* __restrict__ w2, const float* __restrict__ b2,
    float* __restrict__ outlog) {
    __shared__ __align__(16) u16 lds[18432];  // 36 KB: A bufs 16 KB; epilogue 36 KB
    int t = threadIdx.x;
    int wv = t >> 6, l = t & 63;
    int q = l >> 4, l16 = l & 15;
    int m0 = blockIdx.x * 64;
    int n0 = wv * 64;
    const int steps = K >> 5;  // 24 or 32 (even)

    f32x4 acc[4][4] = {};  // [mh][nt]

    int arow = min(m0 + wv * 16 + l16, NN - 1);  // wave wv stages A frag mh=wv

    auto stageA = [&](int buf, int s) {
        int kt = s * 32;
        int ch = kt >> 8;  // wave-uniform -> SGPR select
        const u16* ap;
        int la;
        if (ch == 0) { ap = A0; la = lda0; }
        else if (ch == 1) { ap = A1; la = lda1; }
        else if (ch == 2) { ap = A2; la = lda2; }
        else { ap = A3; la = lda3; }
        gll16(ap + (size_t)arow * la + (kt & 255) + q * 8, lds + buf * 2048 + wv * 512);
    };

    const u16* bfw = Bf + (size_t)(wv * 4) * 512 + l * 8;  // wave frag base + lane
    auto loadB = [&](bf16x8* dst, int s) {
#pragma unroll
        for (int j = 0; j < 4; j++)
            dst[j] = *(const bf16x8*)(bfw + (size_t)s * 8192 + j * 512);
    };
    auto comp = [&](int buf, const bf16x8* b) {
        const u16* base = lds + buf * 2048;
        bf16x8 a[4];
#pragma unroll
        for (int mh = 0; mh < 4; mh++)
            a[mh] = *(const bf16x8*)(base + mh * 512 + l * 8);
#pragma unroll
        for (int mh = 0; mh < 4; mh++)
#pragma unroll
            for (int j = 0; j < 4; j++)
                acc[mh][j] =
                    __builtin_amdgcn_mfma_f32_16x16x32_bf16(a[mh], b[j], acc[mh][j], 0, 0, 0);
    };

    bf16x8 bA[4], bB[4];
    loadB(bA, 0);            // B(0) first: A prefetch queue stays behind it
    stageA(0, 0);
    stageA(1, 1);
    stageA(2, 2);
    for (int s = 0; s < steps; s += 2) {
        // ---- even sub-iter: compute with bA, prefetch bB = B(s+1) ----
        if (s == 0)               asm volatile("s_waitcnt vmcnt(2)" ::: "memory");
        else if (s == steps - 2)  asm volatile("s_waitcnt vmcnt(9)" ::: "memory");
        else                      asm volatile("s_waitcnt vmcnt(10)" ::: "memory");
        __builtin_amdgcn_s_barrier();  // A buf s&3 complete in all waves
        __builtin_amdgcn_sched_barrier(0);
        loadB(bB, s + 1);  // s+1 < steps always (s <= steps-2)
        __builtin_amdgcn_sched_barrier(0);
        if (s + 3 < steps) stageA((s + 3) & 3, s + 3);
        __builtin_amdgcn_sched_barrier(0);
        comp(s & 3, bA);
        // ---- odd sub-iter: compute with bB, prefetch bA = B(s+2) ----
        if (s == 0)               asm volatile("s_waitcnt vmcnt(6)" ::: "memory");
        else if (s == steps - 2)  asm volatile("s_waitcnt vmcnt(8)" ::: "memory");
        else                      asm volatile("s_waitcnt vmcnt(10)" ::: "memory");
        __builtin_amdgcn_s_barrier();
        __builtin_amdgcn_sched_barrier(0);
        if (s + 2 < steps) loadB(bA, s + 2);
        __builtin_amdgcn_sched_barrier(0);
        if (s + 4 < steps) stageA((s + 4) & 3, s + 4);
        __builtin_amdgcn_sched_barrier(0);
        comp((s + 1) & 3, bB);
    }
    __syncthreads();  // all waves done with K-loop LDS; reuse below

    if (mode == 0) {
        u16* Cs = lds + wv * 4608;  // per-wave [64][72] (9216 B x4 = 36 KB)
#pragma unroll
        for (int mh = 0; mh < 4; mh++)
#pragma unroll
            for (int j = 0; j < 4; j++)
#pragma unroll
                for (int i = 0; i < 4; i++) {
                    float v = acc[mh][j][i];
                    v = v > 0.f ? v : 0.f;
                    Cs[(mh * 16 + q * 4 + i) * 72 + j * 16 + l16] = f2bf(v);
                }
        // same-wave ds_write->ds_read ordered via lgkmcnt
#pragma unroll
        for (int j = 0; j < 8; j++) {
            int f = j * 64 + l;
            int r = f >> 3, cc = (f & 7) * 8;
            uint4 cv = *(const uint4*)&Cs[r * 72 + cc];
            int row = m0 + r;
            if (row < NN) *(uint4*)(outb + (size_t)row * ldob + n0 + cc) = cv;
        }
    } else {
        float bi[4], s4[4], h4[4], wa[4], wb[4];
#pragma unroll
        for (int j = 0; j < 4; j++) {
            int col = n0 + j * 16 + l16;
            bi[j] = bias[col];
            s4[j] = sc[col];
            h4[j] = sh[col];
            wa[j] = w2[2 * col];
            wb[j] = w2[2 * col + 1];
        }
        float* red = (float*)lds;  // [4 waves][64 rows][2]
#pragma unroll
        for (int mh = 0; mh < 4; mh++)
#pragma unroll
            for (int i = 0; i < 4; i++) {
                float p0 = 0.f, p1 = 0.f;
#pragma unroll
                for (int j = 0; j < 4; j++) {
                    float v = acc[mh][j][i] + bi[j];
                    v = v > 0.f ? v : 0.f;
                    v = v * s4[j] + h4[j];
                    p0 += v * wa[j];
                    p1 += v * wb[j];
                }
#pragma unroll
                for (int off = 1; off < 16; off <<= 1) {
                    p0 += __shfl_xor(p0, off, 64);
                    p1 += __shfl_xor(p1, off, 64);
                }
                if (l16 == 0) {
                    int rl = mh * 16 + q * 4 + i;
                    red[(wv * 64 + rl) * 2 + 0] = p0;
                    red[(wv * 64 + rl) * 2 + 1] = p1;
                }
            }
        __syncthreads();
        if (t < 128) {
            int rl = t >> 1, cp = t & 1;
            float v = red[(0 * 64 + rl) * 2 + cp] + red[(1 * 64 + rl) * 2 + cp] +
                      red[(2 * 64 + rl) * 2 + cp] + red[(3 * 64 + rl) * 2 + cp];
            int row = m0 + rl;
            if (row < NN) outlog[(size_t)row * 2 + cp] = v + b2[cp];
        }
    }
}

extern "C" void kernel_launch(void* const* d_in, const int* in_sizes, int n_in,
                              void* d_out, int out_size, void* d_ws, size_t ws_size,
                              hipStream_t stream) {
    const float* features = (const float*)d_in[0];
    const int* ei = (const int*)d_in[1];
    // d_in[2] = edgenet_input (bypassed by edge_weight_override)
    const float* ew = (const float*)d_in[3];
    const float* cheb_w = (const float*)d_in[4];
    const float* w1 = (const float*)d_in[5];
    const float* b1 = (const float*)d_in[6];
    const float* g = (const float*)d_in[7];
    const float* be = (const float*)d_in[8];
    const float* mn = (const float*)d_in[9];
    const float* vr = (const float*)d_in[10];
    const float* w2 = (const float*)d_in[11];
    const float* b2 = (const float*)d_in[12];
    float* out = (float*)d_out;  // [NN*2] logits, then [EE] ew

    char* p = (char*)d_ws;
    auto alloc = [&](size_t bytes) -> char* {
        char* r = p;
        p += (bytes + 255) & ~(size_t)255;
        return r;
    };
    float* deg = (float*)alloc((size_t)NN * 4);
    int* counts = (int*)alloc((size_t)(NN + 1) * 4);
    int* cursor = (int*)alloc((size_t)NN * 4);
    size_t zero_bytes = (size_t)(p - (char*)deg);
    int* offs = (int*)alloc((size_t)(NN + 1) * 4);
    int2* nbrs = (int2*)alloc((size_t)(EE + 16) * 8);
    u16* xb = (u16*)alloc((size_t)NN * 256 * 2);
    u16* tx1 = (u16*)alloc((size_t)NN * 256 * 2);
    u16* tx2 = (u16*)alloc((size_t)NN * 256 * 2);
    u16* jk = (u16*)alloc((size_t)NN * 1024 * 2);
    u16* chebT = (u16*)alloc((size_t)LGN * 3 * 256 * 256 * 2);  // per layer frag-tiled [768K]
    u16* w1T = (u16*)alloc((size_t)1024 * 256 * 2);             // frag-tiled [1024K]
    float* sc = (float*)alloc(256 * 4);
    float* sh = (float*)alloc(256 * 4);

    hipMemsetAsync(deg, 0, zero_bytes, stream);
    hipMemsetAsync(nbrs + EE, 0, 16 * sizeof(int2), stream);  // safe overrun pad
    k_edge1<<<(EE + 255) / 256, 256, 0, stream>>>(ei, ew, deg, counts, out + (size_t)NN * 2);
    k_scan<<<1, 1024, 0, stream>>>(counts, offs);
    k_scatter<<<(EE + 255) / 256, 256, 0, stream>>>(ei, ew, deg, offs, cursor, nbrs);
    k_cast<<<((NN * 256) + 255) / 256, 256, 0, stream>>>(features, xb, NN * 256);
    k_castB<<<dim3(96, LGN), 256, 0, stream>>>(cheb_w, chebT, 768);
    k_castB<<<dim3(128, 1), 256, 0, stream>>>(w1, w1T, 1024);
    k_foldbn<<<1, 256, 0, stream>>>(g, be, mn, vr, sc, sh);

    const int gg = (NN + 63) / 64;  // 313 blocks (tile M=64 x N=256)
    const int pg = (NN / 4) * 4;    // 20000 blocks: 4 nodes x 4 col-slices
    for (int i = 0; i < LGN; i++) {
        const u16* x = (i == 0) ? xb : (jk + (size_t)(i - 1) * 256);
        int ldx = (i == 0) ? 256 : 1024;
        k_prop<<<pg, 256, 0, stream>>>(x, ldx, (const u16*)nullptr, 0, 0, tx1, 256, offs,
                                       nbrs);
        k_prop<<<pg, 256, 0, stream>>>(tx1, 256, x, ldx, 1, tx2, 256, offs, nbrs);
        k_gemm<<<gg, 256, 0, stream>>>(
            x, tx1, tx2, (const u16*)nullptr, ldx, 256, 256, 0, 768,
            chebT + (size_t)i * 256 * 768, 0, jk + (size_t)i * 256, 1024, (const float*)nullptr,
            (const float*)nullptr, (const float*)nullptr, (const float*)nullptr,
            (const float*)nullptr, (float*)nullptr);
    }
    k_gemm<<<gg, 256, 0, stream>>>(jk, jk + 256, jk + 512, jk + 768, 1024, 1024, 1024, 1024,
                                   1024, w1T, 1, (u16*)nullptr, 0, b1, sc, sh, w2, b2, out);
}

// Round 6
// 456.198 us; speedup vs baseline: 1.1600x; 1.1582x over previous
//
#include <hip/hip_runtime.h>
#include <hip/hip_bf16.h>

#define NN 20000
#define EE 320000
#define LGN 4

typedef unsigned short u16;
typedef short bf16x8 __attribute__((ext_vector_type(8)));
typedef float f32x4 __attribute__((ext_vector_type(4)));

__device__ __forceinline__ float bf2f(u16 v) {
    unsigned int u = ((unsigned int)v) << 16;
    float f; __builtin_memcpy(&f, &u, 4); return f;
}
__device__ __forceinline__ u16 f2bf(float f) {
    __hip_bfloat16 h = __float2bfloat16(f);
    u16 u; __builtin_memcpy(&u, &h, 2); return u;
}

// async global->LDS, 16B per lane, LDS dest = wave-uniform base + lane*16
__device__ __forceinline__ void gll16(const void* g, void* l) {
    __builtin_amdgcn_global_load_lds(
        (const __attribute__((address_space(1))) unsigned int*)g,
        (__attribute__((address_space(3))) unsigned int*)l, 16, 0, 0);
}

// ---- pass 1: degree (by source), col histogram, ew copy-out ----
__global__ __launch_bounds__(256) void k_edge1(const int* __restrict__ ei,
                                               const float* __restrict__ ew,
                                               float* __restrict__ deg,
                                               int* __restrict__ counts,
                                               float* __restrict__ out_ew) {
    int e = blockIdx.x * 256 + threadIdx.x;
    if (e >= EE) return;
    int r = ei[e];
    float w = ew[e];
    atomicAdd(&deg[r], w);
    atomicAdd(&counts[ei[EE + e]], 1);
    out_ew[e] = w;
}

// ---- exclusive scan of col histogram (single block) ----
__global__ __launch_bounds__(1024) void k_scan(const int* __restrict__ counts,
                                               int* __restrict__ offs) {
    __shared__ int part[1024];
    int t = threadIdx.x;
    const int C = (NN + 1023) / 1024;  // 20
    int lo = t * C, hi = min(lo + C, NN);
    int s = 0;
    for (int i = lo; i < hi; i++) s += counts[i];
    part[t] = s;
    __syncthreads();
    for (int off = 1; off < 1024; off <<= 1) {
        int add = (t >= off) ? part[t - off] : 0;
        __syncthreads();
        part[t] += add;
        __syncthreads();
    }
    int base = part[t] - s;
    for (int i = lo; i < hi; i++) { offs[i] = base; base += counts[i]; }
    if (t == 1023) offs[NN] = part[1023];
}

// ---- pass 2: compute norm (rsqrt folded in), scatter into CSR slots ----
__global__ __launch_bounds__(256) void k_scatter(const int* __restrict__ ei,
                                                 const float* __restrict__ ew,
                                                 const float* __restrict__ deg,
                                                 const int* __restrict__ offs,
                                                 int* __restrict__ cursor,
                                                 int2* __restrict__ nbrs) {
    int e = blockIdx.x * 256 + threadIdx.x;
    if (e >= EE) return;
    int r = ei[e], c = ei[EE + e];
    float dr = deg[r], dc = deg[c];
    float ir = (dr > 0.f) ? rsqrtf(dr) : 0.f;
    float ic = (dc > 0.f) ? rsqrtf(dc) : 0.f;
    float nm = -(ir * ew[e] * ic);
    int pidx = offs[c] + atomicAdd(&cursor[c], 1);
    nbrs[pidx] = make_int2(r, __float_as_int(nm));
}

// ---- f32 -> bf16 cast (no transpose) ----
__global__ __launch_bounds__(256) void k_cast(const float* __restrict__ src,
                                              u16* __restrict__ dst, int n) {
    int i = blockIdx.x * 256 + threadIdx.x;
    if (i < n) dst[i] = f2bf(src[i]);
}

// ---- f32 [K][256] -> bf16 fragment-tiled Bf layout ----
// Bf: per (k-step s of 32, n-frag f of 16 cols) one 1KB chunk; lane l owns
// 16B = B[col=f*16+(l&15)][k=s*32+(l>>4)*8 .. +7]. grid.y = weight set.
__global__ __launch_bounds__(256) void k_castB(const float* __restrict__ src,
                                               u16* __restrict__ dst, int K) {
    src += (size_t)blockIdx.y * K * 256;
    dst += (size_t)blockIdx.y * K * 256;
    int tid = blockIdx.x * 256 + threadIdx.x;
    if (tid >= (K >> 5) * 1024) return;
    int l = tid & 63, f = (tid >> 6) & 15, s = tid >> 10;
    int col = f * 16 + (l & 15);
    int kb = s * 32 + ((l >> 4) << 3);
    u16 tmp[8];
#pragma unroll
    for (int j = 0; j < 8; j++) tmp[j] = f2bf(src[(size_t)(kb + j) * 256 + col]);
    *(uint4*)(dst + (size_t)tid * 8) = *(uint4*)tmp;
}

// ---- fold BN affine: s = gamma*rsqrt(var+eps), t = beta - mean*s ----
__global__ __launch_bounds__(256) void k_foldbn(const float* __restrict__ g,
                                                const float* __restrict__ be,
                                                const float* __restrict__ mn,
                                                const float* __restrict__ vr,
                                                float* __restrict__ sc,
                                                float* __restrict__ sh) {
    int t = threadIdx.x;
    if (t < 256) {
        float s = g[t] * rsqrtf(vr[t] + 1e-5f);
        sc[t] = s;
        sh[t] = be[t] - mn[t] * s;
    }
}

// ---- CSR SpMM: one WAVE per node (R13 measured-best form) ----
// 16 gathers in flight (2 batches of 8; second batch wave-uniform gated).
__global__ __launch_bounds__(256) void k_prop(const u16* __restrict__ x, int ldx,
                                              const u16* __restrict__ xsub, int ldsub,
                                              int dotx2,
                                              u16* __restrict__ out, int ldo,
                                              const int* __restrict__ offs,
                                              const int2* __restrict__ nbrs) {
    int c = __builtin_amdgcn_readfirstlane(blockIdx.x * 4 + (threadIdx.x >> 6));
    int lane = threadIdx.x & 63;
    int s = offs[c], e = offs[c + 1];
    float a0 = 0.f, a1 = 0.f, a2 = 0.f, a3 = 0.f;
    for (int i = s; i < e; i += 16) {
        int2 mm[16];
        ushort4 xv[16];
#pragma unroll
        for (int j = 0; j < 8; j++) mm[j] = nbrs[i + j];
#pragma unroll
        for (int j = 0; j < 8; j++)
            xv[j] = *(const ushort4*)(x + (size_t)mm[j].x * ldx + lane * 4);
        bool more = (i + 8 < e);  // wave-uniform (c uniform)
        if (more) {
#pragma unroll
            for (int j = 8; j < 16; j++) mm[j] = nbrs[i + j];
#pragma unroll
            for (int j = 8; j < 16; j++)
                xv[j] = *(const ushort4*)(x + (size_t)mm[j].x * ldx + lane * 4);
        }
#pragma unroll
        for (int j = 0; j < 8; j++) {
            float w = (i + j < e) ? __int_as_float(mm[j].y) : 0.f;
            a0 += w * bf2f(xv[j].x);
            a1 += w * bf2f(xv[j].y);
            a2 += w * bf2f(xv[j].z);
            a3 += w * bf2f(xv[j].w);
        }
        if (more) {
#pragma unroll
            for (int j = 8; j < 16; j++) {
                float w = (i + j < e) ? __int_as_float(mm[j].y) : 0.f;
                a0 += w * bf2f(xv[j].x);
                a1 += w * bf2f(xv[j].y);
                a2 += w * bf2f(xv[j].z);
                a3 += w * bf2f(xv[j].w);
            }
        }
    }
    if (dotx2) {
        ushort4 xs = *(const ushort4*)(xsub + (size_t)c * ldsub + lane * 4);
        a0 = 2.f * a0 - bf2f(xs.x);
        a1 = 2.f * a1 - bf2f(xs.y);
        a2 = 2.f * a2 - bf2f(xs.z);
        a3 = 2.f * a3 - bf2f(xs.w);
    }
    ushort4 o;
    o.x = f2bf(a0); o.y = f2bf(a1); o.z = f2bf(a2); o.w = f2bf(a3);
    *(ushort4*)(out + (size_t)c * ldo + lane * 4) = o;
}

// ---- bf16 MFMA GEMM, R17: tile M=32 x N=256, 128 thr / 2 waves ----
// Same as R16 (grid 625 for balanced CU rounds) with the mode-0 writeback
// FIXED: per-wave tile is 32x128 = 512 8-elem chunks -> jj < 8 (R16 had
// jj < 4, storing only rows 0..15 -> absmax 20). vmcnt audit unchanged:
// head 2/10, steady 18, tail 17/16 (full timeline re-verified for steps=24).
__global__ __launch_bounds__(128, 2) void k_gemm(
    const u16* __restrict__ A0, const u16* __restrict__ A1,
    const u16* __restrict__ A2, const u16* __restrict__ A3,
    int lda0, int lda1, int lda2, int lda3,
    int K, const u16* __restrict__ Bf,
    int mode,
    u16* __restrict__ outb, int ldob,
    const float* __restrict__ bias, const float* __restrict__ sc,
    const float* __restrict__ sh,
    const float* __restrict__ w2, const float* __restrict__ b2,
    float* __restrict__ outlog) {
    __shared__ __align__(16) u16 lds[8704];  // A: [0,4096) 4 bufs x 2KB; epi 17.4KB
    int t = threadIdx.x;
    int wv = t >> 6, l = t & 63;
    int q = l >> 4, l16 = l & 15;
    int m0 = blockIdx.x * 32;
    int n0 = wv * 128;
    const int steps = K >> 5;  // 24 or 32 (even, >=6)

    f32x4 acc[2][8] = {};  // [mh][nt]

    int arow = min(m0 + wv * 16 + l16, NN - 1);  // wave wv stages a-frag wv

    auto stageA = [&](int buf, int s) {
        int kt = s * 32;
        int ch = kt >> 8;  // wave-uniform -> SGPR select
        const u16* ap;
        int la;
        if (ch == 0) { ap = A0; la = lda0; }
        else if (ch == 1) { ap = A1; la = lda1; }
        else if (ch == 2) { ap = A2; la = lda2; }
        else { ap = A3; la = lda3; }
        gll16(ap + (size_t)arow * la + (kt & 255) + q * 8, lds + buf * 1024 + wv * 512);
    };

    const u16* bfw = Bf + (size_t)(wv * 8) * 512 + l * 8;  // wave frag base + lane
    auto loadB = [&](bf16x8* dst, int s) {
#pragma unroll
        for (int j = 0; j < 8; j++)
            dst[j] = *(const bf16x8*)(bfw + (size_t)s * 8192 + j * 512);
    };
    auto comp = [&](int buf, const bf16x8* b) {
        const u16* base = lds + buf * 1024;
        bf16x8 a[2];
#pragma unroll
        for (int mh = 0; mh < 2; mh++)
            a[mh] = *(const bf16x8*)(base + mh * 512 + l * 8);
#pragma unroll
        for (int mh = 0; mh < 2; mh++)
#pragma unroll
            for (int j = 0; j < 8; j++)
                acc[mh][j] =
                    __builtin_amdgcn_mfma_f32_16x16x32_bf16(a[mh], b[j], acc[mh][j], 0, 0, 0);
    };

    bf16x8 bA[8], bB[8];
    loadB(bA, 0);            // B(0) first: A queue stays behind it
    stageA(0, 0);
    stageA(1, 1);
    stageA(2, 2);
    for (int s = 0; s < steps; s += 2) {
        // ---- even sub-iter: compute with bA, prefetch bB = B(s+1) ----
        if (s == 0)               asm volatile("s_waitcnt vmcnt(2)" ::: "memory");
        else if (s == steps - 2)  asm volatile("s_waitcnt vmcnt(17)" ::: "memory");
        else                      asm volatile("s_waitcnt vmcnt(18)" ::: "memory");
        __builtin_amdgcn_s_barrier();  // A buf s&3 complete in all waves
        __builtin_amdgcn_sched_barrier(0);
        loadB(bB, s + 1);  // s+1 < steps always
        __builtin_amdgcn_sched_barrier(0);
        if (s + 3 < steps) stageA((s + 3) & 3, s + 3);
        __builtin_amdgcn_sched_barrier(0);
        comp(s & 3, bA);
        // ---- odd sub-iter: compute with bB, prefetch bA = B(s+2) ----
        if (s == 0)               asm volatile("s_waitcnt vmcnt(10)" ::: "memory");
        else if (s == steps - 2)  asm volatile("s_waitcnt vmcnt(16)" ::: "memory");
        else                      asm volatile("s_waitcnt vmcnt(18)" ::: "memory");
        __builtin_amdgcn_s_barrier();
        __builtin_amdgcn_sched_barrier(0);
        if (s + 2 < steps) loadB(bA, s + 2);
        __builtin_amdgcn_sched_barrier(0);
        if (s + 4 < steps) stageA((s + 4) & 3, s + 4);
        __builtin_amdgcn_sched_barrier(0);
        comp((s + 1) & 3, bB);
    }
    __syncthreads();  // all waves done with K-loop LDS; reuse below

    if (mode == 0) {
        u16* Cs = lds + wv * 4352;  // per-wave [32][136] u16 (8704B x2 = 17408B)
#pragma unroll
        for (int mh = 0; mh < 2; mh++)
#pragma unroll
            for (int j = 0; j < 8; j++)
#pragma unroll
                for (int i = 0; i < 4; i++) {
                    float v = acc[mh][j][i];
                    v = v > 0.f ? v : 0.f;
                    Cs[(mh * 16 + q * 4 + i) * 136 + j * 16 + l16] = f2bf(v);
                }
        // same-wave ds_write->ds_read ordered via lgkmcnt.
        // 32 rows x 128 cols = 512 chunks of 8 -> jj < 8 (R16 bug: jj < 4).
#pragma unroll
        for (int jj = 0; jj < 8; jj++) {
            int f = jj * 64 + l;
            int r = f >> 4, cc = (f & 15) * 8;
            uint4 cv = *(const uint4*)&Cs[r * 136 + cc];
            int row = m0 + r;
            if (row < NN) *(uint4*)(outb + (size_t)row * ldob + n0 + cc) = cv;
        }
    } else {
        float bi[8], s4[8], h4[8], wa[8], wb[8];
#pragma unroll
        for (int j = 0; j < 8; j++) {
            int col = n0 + j * 16 + l16;
            bi[j] = bias[col];
            s4[j] = sc[col];
            h4[j] = sh[col];
            wa[j] = w2[2 * col];
            wb[j] = w2[2 * col + 1];
        }
        float* red = (float*)lds;  // [2 waves][32 rows][2]
#pragma unroll
        for (int mh = 0; mh < 2; mh++)
#pragma unroll
            for (int i = 0; i < 4; i++) {
                float p0 = 0.f, p1 = 0.f;
#pragma unroll
                for (int j = 0; j < 8; j++) {
                    float v = acc[mh][j][i] + bi[j];
                    v = v > 0.f ? v : 0.f;
                    v = v * s4[j] + h4[j];
                    p0 += v * wa[j];
                    p1 += v * wb[j];
                }
#pragma unroll
                for (int off = 1; off < 16; off <<= 1) {
                    p0 += __shfl_xor(p0, off, 64);
                    p1 += __shfl_xor(p1, off, 64);
                }
                if (l16 == 0) {
                    int rl = mh * 16 + q * 4 + i;
                    red[(wv * 32 + rl) * 2 + 0] = p0;
                    red[(wv * 32 + rl) * 2 + 1] = p1;
                }
            }
        __syncthreads();
        if (t < 64) {
            int rl = t >> 1, cp = t & 1;
            float v = red[(0 * 32 + rl) * 2 + cp] + red[(1 * 32 + rl) * 2 + cp];
            int row = m0 + rl;
            if (row < NN) outlog[(size_t)row * 2 + cp] = v + b2[cp];
        }
    }
}

extern "C" void kernel_launch(void* const* d_in, const int* in_sizes, int n_in,
                              void* d_out, int out_size, void* d_ws, size_t ws_size,
                              hipStream_t stream) {
    const float* features = (const float*)d_in[0];
    const int* ei = (const int*)d_in[1];
    // d_in[2] = edgenet_input (bypassed by edge_weight_override)
    const float* ew = (const float*)d_in[3];
    const float* cheb_w = (const float*)d_in[4];
    const float* w1 = (const float*)d_in[5];
    const float* b1 = (const float*)d_in[6];
    const float* g = (const float*)d_in[7];
    const float* be = (const float*)d_in[8];
    const float* mn = (const float*)d_in[9];
    const float* vr = (const float*)d_in[10];
    const float* w2 = (const float*)d_in[11];
    const float* b2 = (const float*)d_in[12];
    float* out = (float*)d_out;  // [NN*2] logits, then [EE] ew

    char* p = (char*)d_ws;
    auto alloc = [&](size_t bytes) -> char* {
        char* r = p;
        p += (bytes + 255) & ~(size_t)255;
        return r;
    };
    float* deg = (float*)alloc((size_t)NN * 4);
    int* counts = (int*)alloc((size_t)(NN + 1) * 4);
    int* cursor = (int*)alloc((size_t)NN * 4);
    size_t zero_bytes = (size_t)(p - (char*)deg);
    int* offs = (int*)alloc((size_t)(NN + 1) * 4);
    int2* nbrs = (int2*)alloc((size_t)(EE + 16) * 8);
    u16* xb = (u16*)alloc((size_t)NN * 256 * 2);
    u16* tx1 = (u16*)alloc((size_t)NN * 256 * 2);
    u16* tx2 = (u16*)alloc((size_t)NN * 256 * 2);
    u16* jk = (u16*)alloc((size_t)NN * 1024 * 2);
    u16* chebT = (u16*)alloc((size_t)LGN * 3 * 256 * 256 * 2);  // per layer frag-tiled
    u16* w1T = (u16*)alloc((size_t)1024 * 256 * 2);             // frag-tiled
    float* sc = (float*)alloc(256 * 4);
    float* sh = (float*)alloc(256 * 4);

    hipMemsetAsync(deg, 0, zero_bytes, stream);
    hipMemsetAsync(nbrs + EE, 0, 16 * sizeof(int2), stream);  // safe overrun pad
    k_edge1<<<(EE + 255) / 256, 256, 0, stream>>>(ei, ew, deg, counts, out + (size_t)NN * 2);
    k_scan<<<1, 1024, 0, stream>>>(counts, offs);
    k_scatter<<<(EE + 255) / 256, 256, 0, stream>>>(ei, ew, deg, offs, cursor, nbrs);
    k_cast<<<((NN * 256) + 255) / 256, 256, 0, stream>>>(features, xb, NN * 256);
    k_castB<<<dim3(96, LGN), 256, 0, stream>>>(cheb_w, chebT, 768);
    k_castB<<<dim3(128, 1), 256, 0, stream>>>(w1, w1T, 1024);
    k_foldbn<<<1, 256, 0, stream>>>(g, be, mn, vr, sc, sh);

    const int gg = (NN + 31) / 32;  // 625 blocks (tile M=32 x N=256, 128 thr)
    for (int i = 0; i < LGN; i++) {
        const u16* x = (i == 0) ? xb : (jk + (size_t)(i - 1) * 256);
        int ldx = (i == 0) ? 256 : 1024;
        k_prop<<<NN / 4, 256, 0, stream>>>(x, ldx, (const u16*)nullptr, 0, 0, tx1, 256, offs,
                                           nbrs);
        k_prop<<<NN / 4, 256, 0, stream>>>(tx1, 256, x, ldx, 1, tx2, 256, offs, nbrs);
        k_gemm<<<gg, 128, 0, stream>>>(
            x, tx1, tx2, (const u16*)nullptr, ldx, 256, 256, 0, 768,
            chebT + (size_t)i * 256 * 768, 0, jk + (size_t)i * 256, 1024, (const float*)nullptr,
            (const float*)nullptr, (const float*)nullptr, (const float*)nullptr,
            (const float*)nullptr, (float*)nullptr);
    }
    k_gemm<<<gg, 128, 0, stream>>>(jk, jk + 256, jk + 512, jk + 768, 1024, 1024, 1024, 1024,
                                   1024, w1T, 1, (u16*)nullptr, 0, b1, sc, sh, w2, b2, out);
}

// Round 9
// 454.124 us; speedup vs baseline: 1.1653x; 1.0046x over previous
//
#include <hip/hip_runtime.h>
#include <hip/hip_bf16.h>

#define NN 20000
#define EE 320000
#define LGN 4

typedef unsigned short u16;
typedef short bf16x8 __attribute__((ext_vector_type(8)));
typedef float f32x4 __attribute__((ext_vector_type(4)));

__device__ __forceinline__ float bf2f(u16 v) {
    unsigned int u = ((unsigned int)v) << 16;
    float f; __builtin_memcpy(&f, &u, 4); return f;
}
__device__ __forceinline__ u16 f2bf(float f) {
    __hip_bfloat16 h = __float2bfloat16(f);
    u16 u; __builtin_memcpy(&u, &h, 2); return u;
}

// async global->LDS, 16B per lane, LDS dest = wave-uniform base + lane*16
__device__ __forceinline__ void gll16(const void* g, void* l) {
    __builtin_amdgcn_global_load_lds(
        (const __attribute__((address_space(1))) unsigned int*)g,
        (__attribute__((address_space(3))) unsigned int*)l, 16, 0, 0);
}

// ---- pass 1: degree (by source), col histogram, ew copy-out ----
__global__ __launch_bounds__(256) void k_edge1(const int* __restrict__ ei,
                                               const float* __restrict__ ew,
                                               float* __restrict__ deg,
                                               int* __restrict__ counts,
                                               float* __restrict__ out_ew) {
    int e = blockIdx.x * 256 + threadIdx.x;
    if (e >= EE) return;
    int r = ei[e];
    float w = ew[e];
    atomicAdd(&deg[r], w);
    atomicAdd(&counts[ei[EE + e]], 1);
    out_ew[e] = w;
}

// ---- exclusive scan of col histogram (single block) ----
__global__ __launch_bounds__(1024) void k_scan(const int* __restrict__ counts,
                                               int* __restrict__ offs) {
    __shared__ int part[1024];
    int t = threadIdx.x;
    const int C = (NN + 1023) / 1024;  // 20
    int lo = t * C, hi = min(lo + C, NN);
    int s = 0;
    for (int i = lo; i < hi; i++) s += counts[i];
    part[t] = s;
    __syncthreads();
    for (int off = 1; off < 1024; off <<= 1) {
        int add = (t >= off) ? part[t - off] : 0;
        __syncthreads();
        part[t] += add;
        __syncthreads();
    }
    int base = part[t] - s;
    for (int i = lo; i < hi; i++) { offs[i] = base; base += counts[i]; }
    if (t == 1023) offs[NN] = part[1023];
}

// ---- pass 2: compute norm (rsqrt folded in), scatter into CSR slots ----
__global__ __launch_bounds__(256) void k_scatter(const int* __restrict__ ei,
                                                 const float* __restrict__ ew,
                                                 const float* __restrict__ deg,
                                                 const int* __restrict__ offs,
                                                 int* __restrict__ cursor,
                                                 int2* __restrict__ nbrs) {
    int e = blockIdx.x * 256 + threadIdx.x;
    if (e >= EE) return;
    int r = ei[e], c = ei[EE + e];
    float dr = deg[r], dc = deg[c];
    float ir = (dr > 0.f) ? rsqrtf(dr) : 0.f;
    float ic = (dc > 0.f) ? rsqrtf(dc) : 0.f;
    float nm = -(ir * ew[e] * ic);
    int pidx = offs[c] + atomicAdd(&cursor[c], 1);
    nbrs[pidx] = make_int2(r, __float_as_int(nm));
}

// ---- f32 -> bf16 cast (no transpose) ----
__global__ __launch_bounds__(256) void k_cast(const float* __restrict__ src,
                                              u16* __restrict__ dst, int n) {
    int i = blockIdx.x * 256 + threadIdx.x;
    if (i < n) dst[i] = f2bf(src[i]);
}

// ---- f32 [K][256] -> bf16 fragment-tiled Bf layout ----
// Bf: per (k-step s of 32, n-frag f of 16 cols) one 1KB chunk; lane l owns
// 16B = B[col=f*16+(l&15)][k=s*32+(l>>4)*8 .. +7]. grid.y = weight set.
__global__ __launch_bounds__(256) void k_castB(const float* __restrict__ src,
                                               u16* __restrict__ dst, int K) {
    src += (size_t)blockIdx.y * K * 256;
    dst += (size_t)blockIdx.y * K * 256;
    int tid = blockIdx.x * 256 + threadIdx.x;
    if (tid >= (K >> 5) * 1024) return;
    int l = tid & 63, f = (tid >> 6) & 15, s = tid >> 10;
    int col = f * 16 + (l & 15);
    int kb = s * 32 + ((l >> 4) << 3);
    u16 tmp[8];
#pragma unroll
    for (int j = 0; j < 8; j++) tmp[j] = f2bf(src[(size_t)(kb + j) * 256 + col]);
    *(uint4*)(dst + (size_t)tid * 8) = *(uint4*)tmp;
}

// ---- fold BN affine: s = gamma*rsqrt(var+eps), t = beta - mean*s ----
__global__ __launch_bounds__(256) void k_foldbn(const float* __restrict__ g,
                                                const float* __restrict__ be,
                                                const float* __restrict__ mn,
                                                const float* __restrict__ vr,
                                                float* __restrict__ sc,
                                                float* __restrict__ sh) {
    int t = threadIdx.x;
    if (t < 256) {
        float s = g[t] * rsqrtf(vr[t] + 1e-5f);
        sc[t] = s;
        sh[t] = be[t] - mn[t] * s;
    }
}

// ---- CSR SpMM: one WAVE per node ----
// R18: prop traffic is fixed at (padded edges) x 512B row-gathers served at
// ~5.7 TB/s (L2-miss-concurrency bound). Old ceil-8 batch gating wasted
// ~3.5-4 w=0 row-gathers per node (~20% of traffic). Now ceil-4: the 16-slot
// two-phase pipeline (all nbr metas, then all gathers, then FMAs) is kept,
// but each 4-slot sub-batch is gated wave-uniformly on (i+4k < e) -- pad
// traffic drops to ~1.5-2 slots (~10% byte cut), load depth for big nodes
// unchanged (up to 16 gathers in flight). Pad nbrs entries are zeroed
// (row 0) and FMA-gated with w=0, as before.
__global__ __launch_bounds__(256) void k_prop(const u16* __restrict__ x, int ldx,
                                              const u16* __restrict__ xsub, int ldsub,
                                              int dotx2,
                                              u16* __restrict__ out, int ldo,
                                              const int* __restrict__ offs,
                                              const int2* __restrict__ nbrs) {
    int c = __builtin_amdgcn_readfirstlane(blockIdx.x * 4 + (threadIdx.x >> 6));
    int lane = threadIdx.x & 63;
    int s = offs[c], e = offs[c + 1];
    float a0 = 0.f, a1 = 0.f, a2 = 0.f, a3 = 0.f;
    for (int i = s; i < e; i += 16) {
        int2 mm[16];
        ushort4 xv[16];
        bool g1 = (i + 4 < e), g2 = (i + 8 < e), g3 = (i + 12 < e);  // wave-uniform
        // phase 1: neighbor metas
#pragma unroll
        for (int j = 0; j < 4; j++) mm[j] = nbrs[i + j];
        if (g1) {
#pragma unroll
            for (int j = 4; j < 8; j++) mm[j] = nbrs[i + j];
        }
        if (g2) {
#pragma unroll
            for (int j = 8; j < 12; j++) mm[j] = nbrs[i + j];
        }
        if (g3) {
#pragma unroll
            for (int j = 12; j < 16; j++) mm[j] = nbrs[i + j];
        }
        // phase 2: row gathers (up to 16 in flight)
#pragma unroll
        for (int j = 0; j < 4; j++)
            xv[j] = *(const ushort4*)(x + (size_t)mm[j].x * ldx + lane * 4);
        if (g1) {
#pragma unroll
            for (int j = 4; j < 8; j++)
                xv[j] = *(const ushort4*)(x + (size_t)mm[j].x * ldx + lane * 4);
        }
        if (g2) {
#pragma unroll
            for (int j = 8; j < 12; j++)
                xv[j] = *(const ushort4*)(x + (size_t)mm[j].x * ldx + lane * 4);
        }
        if (g3) {
#pragma unroll
            for (int j = 12; j < 16; j++)
                xv[j] = *(const ushort4*)(x + (size_t)mm[j].x * ldx + lane * 4);
        }
        // phase 3: FMAs (per-edge exact w gating within issued sub-batches)
#pragma unroll
        for (int j = 0; j < 4; j++) {
            float w = (i + j < e) ? __int_as_float(mm[j].y) : 0.f;
            a0 += w * bf2f(xv[j].x);
            a1 += w * bf2f(xv[j].y);
            a2 += w * bf2f(xv[j].z);
            a3 += w * bf2f(xv[j].w);
        }
        if (g1) {
#pragma unroll
            for (int j = 4; j < 8; j++) {
                float w = (i + j < e) ? __int_as_float(mm[j].y) : 0.f;
                a0 += w * bf2f(xv[j].x);
                a1 += w * bf2f(xv[j].y);
                a2 += w * bf2f(xv[j].z);
                a3 += w * bf2f(xv[j].w);
            }
        }
        if (g2) {
#pragma unroll
            for (int j = 8; j < 12; j++) {
                float w = (i + j < e) ? __int_as_float(mm[j].y) : 0.f;
                a0 += w * bf2f(xv[j].x);
                a1 += w * bf2f(xv[j].y);
                a2 += w * bf2f(xv[j].z);
                a3 += w * bf2f(xv[j].w);
            }
        }
        if (g3) {
#pragma unroll
            for (int j = 12; j < 16; j++) {
                float w = (i + j < e) ? __int_as_float(mm[j].y) : 0.f;
                a0 += w * bf2f(xv[j].x);
                a1 += w * bf2f(xv[j].y);
                a2 += w * bf2f(xv[j].z);
                a3 += w * bf2f(xv[j].w);
            }
        }
    }
    if (dotx2) {
        ushort4 xs = *(const ushort4*)(xsub + (size_t)c * ldsub + lane * 4);
        a0 = 2.f * a0 - bf2f(xs.x);
        a1 = 2.f * a1 - bf2f(xs.y);
        a2 = 2.f * a2 - bf2f(xs.z);
        a3 = 2.f * a3 - bf2f(xs.w);
    }
    ushort4 o;
    o.x = f2bf(a0); o.y = f2bf(a1); o.z = f2bf(a2); o.w = f2bf(a3);
    *(ushort4*)(out + (size_t)c * ldo + lane * 4) = o;
}

// ---- bf16 MFMA GEMM, R17 form (unchanged): tile M=32 x N=256, 2 waves ----
// Grid 625. Wave wv owns rows m0..m0+31 x cols wv*128..+127: 2 a-frags x 8
// b-frags = 16 MFMA/step. A: 1 gll16/wave/step, quad-buffered depth-3. B:
// register ping-pong from frag-tiled Bf. vmcnt: head 2/10, steady 18, tail
// 17/16 (audited). mode-0 writeback jj<8 (32x128 tile = 512 chunks).
__global__ __launch_bounds__(128, 2) void k_gemm(
    const u16* __restrict__ A0, const u16* __restrict__ A1,
    const u16* __restrict__ A2, const u16* __restrict__ A3,
    int lda0, int lda1, int lda2, int lda3,
    int K, const u16* __restrict__ Bf,
    int mode,
    u16* __restrict__ outb, int ldob,
    const float* __restrict__ bias, const float* __restrict__ sc,
    const float* __restrict__ sh,
    const float* __restrict__ w2, const float* __restrict__ b2,
    float* __restrict__ outlog) {
    __shared__ __align__(16) u16 lds[8704];  // A: [0,4096) 4 bufs x 2KB; epi 17.4KB
    int t = threadIdx.x;
    int wv = t >> 6, l = t & 63;
    int q = l >> 4, l16 = l & 15;
    int m0 = blockIdx.x * 32;
    int n0 = wv * 128;
    const int steps = K >> 5;  // 24 or 32 (even, >=6)

    f32x4 acc[2][8] = {};  // [mh][nt]

    int arow = min(m0 + wv * 16 + l16, NN - 1);  // wave wv stages a-frag wv

    auto stageA = [&](int buf, int s) {
        int kt = s * 32;
        int ch = kt >> 8;  // wave-uniform -> SGPR select
        const u16* ap;
        int la;
        if (ch == 0) { ap = A0; la = lda0; }
        else if (ch == 1) { ap = A1; la = lda1; }
        else if (ch == 2) { ap = A2; la = lda2; }
        else { ap = A3; la = lda3; }
        gll16(ap + (size_t)arow * la + (kt & 255) + q * 8, lds + buf * 1024 + wv * 512);
    };

    const u16* bfw = Bf + (size_t)(wv * 8) * 512 + l * 8;  // wave frag base + lane
    auto loadB = [&](bf16x8* dst, int s) {
#pragma unroll
        for (int j = 0; j < 8; j++)
            dst[j] = *(const bf16x8*)(bfw + (size_t)s * 8192 + j * 512);
    };
    auto comp = [&](int buf, const bf16x8* b) {
        const u16* base = lds + buf * 1024;
        bf16x8 a[2];
#pragma unroll
        for (int mh = 0; mh < 2; mh++)
            a[mh] = *(const bf16x8*)(base + mh * 512 + l * 8);
#pragma unroll
        for (int mh = 0; mh < 2; mh++)
#pragma unroll
            for (int j = 0; j < 8; j++)
                acc[mh][j] =
                    __builtin_amdgcn_mfma_f32_16x16x32_bf16(a[mh], b[j], acc[mh][j], 0, 0, 0);
    };

    bf16x8 bA[8], bB[8];
    loadB(bA, 0);            // B(0) first: A queue stays behind it
    stageA(0, 0);
    stageA(1, 1);
    stageA(2, 2);
    for (int s = 0; s < steps; s += 2) {
        // ---- even sub-iter: compute with bA, prefetch bB = B(s+1) ----
        if (s == 0)               asm volatile("s_waitcnt vmcnt(2)" ::: "memory");
        else if (s == steps - 2)  asm volatile("s_waitcnt vmcnt(17)" ::: "memory");
        else                      asm volatile("s_waitcnt vmcnt(18)" ::: "memory");
        __builtin_amdgcn_s_barrier();  // A buf s&3 complete in all waves
        __builtin_amdgcn_sched_barrier(0);
        loadB(bB, s + 1);  // s+1 < steps always
        __builtin_amdgcn_sched_barrier(0);
        if (s + 3 < steps) stageA((s + 3) & 3, s + 3);
        __builtin_amdgcn_sched_barrier(0);
        comp(s & 3, bA);
        // ---- odd sub-iter: compute with bB, prefetch bA = B(s+2) ----
        if (s == 0)               asm volatile("s_waitcnt vmcnt(10)" ::: "memory");
        else if (s == steps - 2)  asm volatile("s_waitcnt vmcnt(16)" ::: "memory");
        else                      asm volatile("s_waitcnt vmcnt(18)" ::: "memory");
        __builtin_amdgcn_s_barrier();
        __builtin_amdgcn_sched_barrier(0);
        if (s + 2 < steps) loadB(bA, s + 2);
        __builtin_amdgcn_sched_barrier(0);
        if (s + 4 < steps) stageA((s + 4) & 3, s + 4);
        __builtin_amdgcn_sched_barrier(0);
        comp((s + 1) & 3, bB);
    }
    __syncthreads();  // all waves done with K-loop LDS; reuse below

    if (mode == 0) {
        u16* Cs = lds + wv * 4352;  // per-wave [32][136] u16 (8704B x2 = 17408B)
#pragma unroll
        for (int mh = 0; mh < 2; mh++)
#pragma unroll
            for (int j = 0; j < 8; j++)
#pragma unroll
                for (int i = 0; i < 4; i++) {
                    float v = acc[mh][j][i];
                    v = v > 0.f ? v : 0.f;
                    Cs[(mh * 16 + q * 4 + i) * 136 + j * 16 + l16] = f2bf(v);
                }
        // same-wave ds_write->ds_read ordered via lgkmcnt.
        // 32 rows x 128 cols = 512 chunks of 8 -> jj < 8.
#pragma unroll
        for (int jj = 0; jj < 8; jj++) {
            int f = jj * 64 + l;
            int r = f >> 4, cc = (f & 15) * 8;
            uint4 cv = *(const uint4*)&Cs[r * 136 + cc];
            int row = m0 + r;
            if (row < NN) *(uint4*)(outb + (size_t)row * ldob + n0 + cc) = cv;
        }
    } else {
        float bi[8], s4[8], h4[8], wa[8], wb[8];
#pragma unroll
        for (int j = 0; j < 8; j++) {
            int col = n0 + j * 16 + l16;
            bi[j] = bias[col];
            s4[j] = sc[col];
            h4[j] = sh[col];
            wa[j] = w2[2 * col];
            wb[j] = w2[2 * col + 1];
        }
        float* red = (float*)lds;  // [2 waves][32 rows][2]
#pragma unroll
        for (int mh = 0; mh < 2; mh++)
#pragma unroll
            for (int i = 0; i < 4; i++) {
                float p0 = 0.f, p1 = 0.f;
#pragma unroll
                for (int j = 0; j < 8; j++) {
                    float v = acc[mh][j][i] + bi[j];
                    v = v > 0.f ? v : 0.f;
                    v = v * s4[j] + h4[j];
                    p0 += v * wa[j];
                    p1 += v * wb[j];
                }
#pragma unroll
                for (int off = 1; off < 16; off <<= 1) {
                    p0 += __shfl_xor(p0, off, 64);
                    p1 += __shfl_xor(p1, off, 64);
                }
                if (l16 == 0) {
                    int rl = mh * 16 + q * 4 + i;
                    red[(wv * 32 + rl) * 2 + 0] = p0;
                    red[(wv * 32 + rl) * 2 + 1] = p1;
                }
            }
        __syncthreads();
        if (t < 64) {
            int rl = t >> 1, cp = t & 1;
            float v = red[(0 * 32 + rl) * 2 + cp] + red[(1 * 32 + rl) * 2 + cp];
            int row = m0 + rl;
            if (row < NN) outlog[(size_t)row * 2 + cp] = v + b2[cp];
        }
    }
}

extern "C" void kernel_launch(void* const* d_in, const int* in_sizes, int n_in,
                              void* d_out, int out_size, void* d_ws, size_t ws_size,
                              hipStream_t stream) {
    const float* features = (const float*)d_in[0];
    const int* ei = (const int*)d_in[1];
    // d_in[2] = edgenet_input (bypassed by edge_weight_override)
    const float* ew = (const float*)d_in[3];
    const float* cheb_w = (const float*)d_in[4];
    const float* w1 = (const float*)d_in[5];
    const float* b1 = (const float*)d_in[6];
    const float* g = (const float*)d_in[7];
    const float* be = (const float*)d_in[8];
    const float* mn = (const float*)d_in[9];
    const float* vr = (const float*)d_in[10];
    const float* w2 = (const float*)d_in[11];
    const float* b2 = (const float*)d_in[12];
    float* out = (float*)d_out;  // [NN*2] logits, then [EE] ew

    char* p = (char*)d_ws;
    auto alloc = [&](size_t bytes) -> char* {
        char* r = p;
        p += (bytes + 255) & ~(size_t)255;
        return r;
    };
    float* deg = (float*)alloc((size_t)NN * 4);
    int* counts = (int*)alloc((size_t)(NN + 1) * 4);
    int* cursor = (int*)alloc((size_t)NN * 4);
    size_t zero_bytes = (size_t)(p - (char*)deg);
    int* offs = (int*)alloc((size_t)(NN + 1) * 4);
    int2* nbrs = (int2*)alloc((size_t)(EE + 16) * 8);
    u16* xb = (u16*)alloc((size_t)NN * 256 * 2);
    u16* tx1 = (u16*)alloc((size_t)NN * 256 * 2);
    u16* tx2 = (u16*)alloc((size_t)NN * 256 * 2);
    u16* jk = (u16*)alloc((size_t)NN * 1024 * 2);
    u16* chebT = (u16*)alloc((size_t)LGN * 3 * 256 * 256 * 2);  // per layer frag-tiled
    u16* w1T = (u16*)alloc((size_t)1024 * 256 * 2);             // frag-tiled
    float* sc = (float*)alloc(256 * 4);
    float* sh = (float*)alloc(256 * 4);

    hipMemsetAsync(deg, 0, zero_bytes, stream);
    hipMemsetAsync(nbrs + EE, 0, 16 * sizeof(int2), stream);  // safe overrun pad
    k_edge1<<<(EE + 255) / 256, 256, 0, stream>>>(ei, ew, deg, counts, out + (size_t)NN * 2);
    k_scan<<<1, 1024, 0, stream>>>(counts, offs);
    k_scatter<<<(EE + 255) / 256, 256, 0, stream>>>(ei, ew, deg, offs, cursor, nbrs);
    k_cast<<<((NN * 256) + 255) / 256, 256, 0, stream>>>(features, xb, NN * 256);
    k_castB<<<dim3(96, LGN), 256, 0, stream>>>(cheb_w, chebT, 768);
    k_castB<<<dim3(128, 1), 256, 0, stream>>>(w1, w1T, 1024);
    k_foldbn<<<1, 256, 0, stream>>>(g, be, mn, vr, sc, sh);

    const int gg = (NN + 31) / 32;  // 625 blocks (tile M=32 x N=256, 128 thr)
    for (int i = 0; i < LGN; i++) {
        const u16* x = (i == 0) ? xb : (jk + (size_t)(i - 1) * 256);
        int ldx = (i == 0) ? 256 : 1024;
        k_prop<<<NN / 4, 256, 0, stream>>>(x, ldx, (const u16*)nullptr, 0, 0, tx1, 256, offs,
                                           nbrs);
        k_prop<<<NN / 4, 256, 0, stream>>>(tx1, 256, x, ldx, 1, tx2, 256, offs, nbrs);
        k_gemm<<<gg, 128, 0, stream>>>(
            x, tx1, tx2, (const u16*)nullptr, ldx, 256, 256, 0, 768,
            chebT + (size_t)i * 256 * 768, 0, jk + (size_t)i * 256, 1024, (const float*)nullptr,
            (const float*)nullptr, (const float*)nullptr, (const float*)nullptr,
            (const float*)nullptr, (float*)nullptr);
    }
    k_gemm<<<gg, 128, 0, stream>>>(jk, jk + 256, jk + 512, jk + 768, 1024, 1024, 1024, 1024,
                                   1024, w1T, 1, (u16*)nullptr, 0, b1, sc, sh, w2, b2, out);
}

// Round 10
// 444.294 us; speedup vs baseline: 1.1911x; 1.0221x over previous
//
#include <hip/hip_runtime.h>
#include <hip/hip_bf16.h>

#define NN 20000
#define EE 320000
#define LGN 4

typedef unsigned short u16;
typedef short bf16x8 __attribute__((ext_vector_type(8)));
typedef float f32x4 __attribute__((ext_vector_type(4)));

__device__ __forceinline__ float bf2f(u16 v) {
    unsigned int u = ((unsigned int)v) << 16;
    float f; __builtin_memcpy(&f, &u, 4); return f;
}
__device__ __forceinline__ u16 f2bf(float f) {
    __hip_bfloat16 h = __float2bfloat16(f);
    u16 u; __builtin_memcpy(&u, &h, 2); return u;
}

// async global->LDS, 16B per lane, LDS dest = wave-uniform base + lane*16
__device__ __forceinline__ void gll16(const void* g, void* l) {
    __builtin_amdgcn_global_load_lds(
        (const __attribute__((address_space(1))) unsigned int*)g,
        (__attribute__((address_space(3))) unsigned int*)l, 16, 0, 0);
}

// ---- pass 1: degree (by source), col histogram, ew copy-out ----
__global__ __launch_bounds__(256) void k_edge1(const int* __restrict__ ei,
                                               const float* __restrict__ ew,
                                               float* __restrict__ deg,
                                               int* __restrict__ counts,
                                               float* __restrict__ out_ew) {
    int e = blockIdx.x * 256 + threadIdx.x;
    if (e >= EE) return;
    int r = ei[e];
    float w = ew[e];
    atomicAdd(&deg[r], w);
    atomicAdd(&counts[ei[EE + e]], 1);
    out_ew[e] = w;
}

// ---- exclusive scan of col histogram (single block) ----
__global__ __launch_bounds__(1024) void k_scan(const int* __restrict__ counts,
                                               int* __restrict__ offs) {
    __shared__ int part[1024];
    int t = threadIdx.x;
    const int C = (NN + 1023) / 1024;  // 20
    int lo = t * C, hi = min(lo + C, NN);
    int s = 0;
    for (int i = lo; i < hi; i++) s += counts[i];
    part[t] = s;
    __syncthreads();
    for (int off = 1; off < 1024; off <<= 1) {
        int add = (t >= off) ? part[t - off] : 0;
        __syncthreads();
        part[t] += add;
        __syncthreads();
    }
    int base = part[t] - s;
    for (int i = lo; i < hi; i++) { offs[i] = base; base += counts[i]; }
    if (t == 1023) offs[NN] = part[1023];
}

// ---- pass 2: compute norm (rsqrt folded in), scatter into CSR slots ----
__global__ __launch_bounds__(256) void k_scatter(const int* __restrict__ ei,
                                                 const float* __restrict__ ew,
                                                 const float* __restrict__ deg,
                                                 const int* __restrict__ offs,
                                                 int* __restrict__ cursor,
                                                 int2* __restrict__ nbrs) {
    int e = blockIdx.x * 256 + threadIdx.x;
    if (e >= EE) return;
    int r = ei[e], c = ei[EE + e];
    float dr = deg[r], dc = deg[c];
    float ir = (dr > 0.f) ? rsqrtf(dr) : 0.f;
    float ic = (dc > 0.f) ? rsqrtf(dc) : 0.f;
    float nm = -(ir * ew[e] * ic);
    int pidx = offs[c] + atomicAdd(&cursor[c], 1);
    nbrs[pidx] = make_int2(r, __float_as_int(nm));
}

// ---- f32 -> bf16 cast (no transpose) ----
__global__ __launch_bounds__(256) void k_cast(const float* __restrict__ src,
                                              u16* __restrict__ dst, int n) {
    int i = blockIdx.x * 256 + threadIdx.x;
    if (i < n) dst[i] = f2bf(src[i]);
}

// ---- f32 [K][256] -> bf16 fragment-tiled Bf layout ----
// Bf: per (k-step s of 32, n-frag f of 16 cols) one 1KB chunk; lane l owns
// 16B = B[col=f*16+(l&15)][k=s*32+(l>>4)*8 .. +7]. grid.y = weight set.
__global__ __launch_bounds__(256) void k_castB(const float* __restrict__ src,
                                               u16* __restrict__ dst, int K) {
    src += (size_t)blockIdx.y * K * 256;
    dst += (size_t)blockIdx.y * K * 256;
    int tid = blockIdx.x * 256 + threadIdx.x;
    if (tid >= (K >> 5) * 1024) return;
    int l = tid & 63, f = (tid >> 6) & 15, s = tid >> 10;
    int col = f * 16 + (l & 15);
    int kb = s * 32 + ((l >> 4) << 3);
    u16 tmp[8];
#pragma unroll
    for (int j = 0; j < 8; j++) tmp[j] = f2bf(src[(size_t)(kb + j) * 256 + col]);
    *(uint4*)(dst + (size_t)tid * 8) = *(uint4*)tmp;
}

// ---- fold BN affine: s = gamma*rsqrt(var+eps), t = beta - mean*s ----
__global__ __launch_bounds__(256) void k_foldbn(const float* __restrict__ g,
                                                const float* __restrict__ be,
                                                const float* __restrict__ mn,
                                                const float* __restrict__ vr,
                                                float* __restrict__ sc,
                                                float* __restrict__ sh) {
    int t = threadIdx.x;
    if (t < 256) {
        float s = g[t] * rsqrtf(vr[t] + 1e-5f);
        sc[t] = s;
        sh[t] = be[t] - mn[t] * s;
    }
}

// ---- CSR SpMM: one WAVE per node (R18 ceil-4 form, kept) ----
__global__ __launch_bounds__(256) void k_prop(const u16* __restrict__ x, int ldx,
                                              const u16* __restrict__ xsub, int ldsub,
                                              int dotx2,
                                              u16* __restrict__ out, int ldo,
                                              const int* __restrict__ offs,
                                              const int2* __restrict__ nbrs) {
    int c = __builtin_amdgcn_readfirstlane(blockIdx.x * 4 + (threadIdx.x >> 6));
    int lane = threadIdx.x & 63;
    int s = offs[c], e = offs[c + 1];
    float a0 = 0.f, a1 = 0.f, a2 = 0.f, a3 = 0.f;
    for (int i = s; i < e; i += 16) {
        int2 mm[16];
        ushort4 xv[16];
        bool g1 = (i + 4 < e), g2 = (i + 8 < e), g3 = (i + 12 < e);  // wave-uniform
#pragma unroll
        for (int j = 0; j < 4; j++) mm[j] = nbrs[i + j];
        if (g1) {
#pragma unroll
            for (int j = 4; j < 8; j++) mm[j] = nbrs[i + j];
        }
        if (g2) {
#pragma unroll
            for (int j = 8; j < 12; j++) mm[j] = nbrs[i + j];
        }
        if (g3) {
#pragma unroll
            for (int j = 12; j < 16; j++) mm[j] = nbrs[i + j];
        }
#pragma unroll
        for (int j = 0; j < 4; j++)
            xv[j] = *(const ushort4*)(x + (size_t)mm[j].x * ldx + lane * 4);
        if (g1) {
#pragma unroll
            for (int j = 4; j < 8; j++)
                xv[j] = *(const ushort4*)(x + (size_t)mm[j].x * ldx + lane * 4);
        }
        if (g2) {
#pragma unroll
            for (int j = 8; j < 12; j++)
                xv[j] = *(const ushort4*)(x + (size_t)mm[j].x * ldx + lane * 4);
        }
        if (g3) {
#pragma unroll
            for (int j = 12; j < 16; j++)
                xv[j] = *(const ushort4*)(x + (size_t)mm[j].x * ldx + lane * 4);
        }
#pragma unroll
        for (int j = 0; j < 4; j++) {
            float w = (i + j < e) ? __int_as_float(mm[j].y) : 0.f;
            a0 += w * bf2f(xv[j].x);
            a1 += w * bf2f(xv[j].y);
            a2 += w * bf2f(xv[j].z);
            a3 += w * bf2f(xv[j].w);
        }
        if (g1) {
#pragma unroll
            for (int j = 4; j < 8; j++) {
                float w = (i + j < e) ? __int_as_float(mm[j].y) : 0.f;
                a0 += w * bf2f(xv[j].x);
                a1 += w * bf2f(xv[j].y);
                a2 += w * bf2f(xv[j].z);
                a3 += w * bf2f(xv[j].w);
            }
        }
        if (g2) {
#pragma unroll
            for (int j = 8; j < 12; j++) {
                float w = (i + j < e) ? __int_as_float(mm[j].y) : 0.f;
                a0 += w * bf2f(xv[j].x);
                a1 += w * bf2f(xv[j].y);
                a2 += w * bf2f(xv[j].z);
                a3 += w * bf2f(xv[j].w);
            }
        }
        if (g3) {
#pragma unroll
            for (int j = 12; j < 16; j++) {
                float w = (i + j < e) ? __int_as_float(mm[j].y) : 0.f;
                a0 += w * bf2f(xv[j].x);
                a1 += w * bf2f(xv[j].y);
                a2 += w * bf2f(xv[j].z);
                a3 += w * bf2f(xv[j].w);
            }
        }
    }
    if (dotx2) {
        ushort4 xs = *(const ushort4*)(xsub + (size_t)c * ldsub + lane * 4);
        a0 = 2.f * a0 - bf2f(xs.x);
        a1 = 2.f * a1 - bf2f(xs.y);
        a2 = 2.f * a2 - bf2f(xs.z);
        a3 = 2.f * a3 - bf2f(xs.w);
    }
    ushort4 o;
    o.x = f2bf(a0); o.y = f2bf(a1); o.z = f2bf(a2); o.w = f2bf(a3);
    *(ushort4*)(out + (size_t)c * ldo + lane * 4) = o;
}

// ---- bf16 MFMA GEMM, R19: tile M=32 x N=256, 128 thr / 2 waves ----
// mode 0: cheb-layer gemm, relu -> bf16 jk slice (R17 proven form).
// mode 2: FUSED layer-3 + classifier. R0 evidence: K=768 and K=1024 gemms
// ran in identical time -> K-loop ~free, cost is per-dispatch. Nothing but
// the classifier reads jk slice 3, so keep h3 on-chip: phase A computes h3
// (24 steps, chebT3), relu->bf16 into shared LDS [32][264] (264 stride:
// 2-way bank aliasing only, free per m136); phase B contracts K=1024 =
// jk slices 0-2 (gll16 pipeline, 24 steps) + h3 from LDS (8 steps, no
// barriers -- FIFO audit: comp(t)'s implicit B-wait retires all stages
// issued <= t-1, so st(s) is always complete before step s's ds_read; the
// barrier covers the cross-wave stage). Then BN/w2 epilogue -> logits.
// Saves: 1 dispatch + 10 MB jk3 write + 10 MB re-read.
__global__ __launch_bounds__(128, 2) void k_gemm(
    const u16* __restrict__ A0, const u16* __restrict__ A1,
    const u16* __restrict__ A2,
    int lda0, int lda1, int lda2,
    int K, const u16* __restrict__ Bf, const u16* __restrict__ Bf2,
    const u16* __restrict__ jkb,
    int mode,
    u16* __restrict__ outb, int ldob,
    const float* __restrict__ bias, const float* __restrict__ sc,
    const float* __restrict__ sh,
    const float* __restrict__ w2, const float* __restrict__ b2,
    float* __restrict__ outlog) {
    // [0,4096): 4 A-bufs x 2KB. [4096,12544): h3 [32][264] (mode 2) or
    // mode-0 epilogue Cs (2 waves x 4352 at offset wv*4352, fits 8704).
    __shared__ __align__(16) u16 lds[12544];  // 25088 B
    int t = threadIdx.x;
    int wv = t >> 6, l = t & 63;
    int q = l >> 4, l16 = l & 15;
    int m0 = blockIdx.x * 32;
    int n0 = wv * 128;
    const int steps = K >> 5;  // 24

    f32x4 acc[2][8] = {};  // [mh][nt]

    int arow = m0 + wv * 16 + l16;  // NN = 625*32 exactly; no clamp needed

    auto stageA = [&](int buf, int s) {
        int kt = s * 32;
        int ch = kt >> 8;  // wave-uniform -> SGPR select
        const u16* ap;
        int la;
        if (ch == 0) { ap = A0; la = lda0; }
        else if (ch == 1) { ap = A1; la = lda1; }
        else { ap = A2; la = lda2; }
        gll16(ap + (size_t)arow * la + (kt & 255) + q * 8, lds + buf * 1024 + wv * 512);
    };

    const u16* bfw = Bf + (size_t)(wv * 8) * 512 + l * 8;  // wave frag base + lane
    auto loadB = [&](bf16x8* dst, int s) {
#pragma unroll
        for (int j = 0; j < 8; j++)
            dst[j] = *(const bf16x8*)(bfw + (size_t)s * 8192 + j * 512);
    };
    auto comp = [&](int buf, const bf16x8* b) {
        const u16* base = lds + buf * 1024;
        bf16x8 a[2];
#pragma unroll
        for (int mh = 0; mh < 2; mh++)
            a[mh] = *(const bf16x8*)(base + mh * 512 + l * 8);
#pragma unroll
        for (int mh = 0; mh < 2; mh++)
#pragma unroll
            for (int j = 0; j < 8; j++)
                acc[mh][j] =
                    __builtin_amdgcn_mfma_f32_16x16x32_bf16(a[mh], b[j], acc[mh][j], 0, 0, 0);
    };

    bf16x8 bA[8], bB[8];
    loadB(bA, 0);            // B(0) first: A queue stays behind it
    stageA(0, 0);
    stageA(1, 1);
    stageA(2, 2);
    for (int s = 0; s < steps; s += 2) {
        if (s == 0)               asm volatile("s_waitcnt vmcnt(2)" ::: "memory");
        else                      asm volatile("s_waitcnt vmcnt(10)" ::: "memory");
        __builtin_amdgcn_s_barrier();
        __builtin_amdgcn_sched_barrier(0);
        loadB(bB, s + 1);
        __builtin_amdgcn_sched_barrier(0);
        if (s + 3 < steps) stageA((s + 3) & 3, s + 3);
        __builtin_amdgcn_sched_barrier(0);
        comp(s & 3, bA);
        asm volatile("s_waitcnt vmcnt(10)" ::: "memory");
        __builtin_amdgcn_s_barrier();
        __builtin_amdgcn_sched_barrier(0);
        if (s + 2 < steps) loadB(bA, s + 2);
        __builtin_amdgcn_sched_barrier(0);
        if (s + 4 < steps) stageA((s + 4) & 3, s + 4);
        __builtin_amdgcn_sched_barrier(0);
        comp((s + 1) & 3, bB);
    }
    __syncthreads();  // all waves done with K-loop LDS; reuse below

    if (mode == 0) {
        u16* Cs = lds + 4096 + wv * 4352;  // per-wave [32][136] u16
#pragma unroll
        for (int mh = 0; mh < 2; mh++)
#pragma unroll
            for (int j = 0; j < 8; j++)
#pragma unroll
                for (int i = 0; i < 4; i++) {
                    float v = acc[mh][j][i];
                    v = v > 0.f ? v : 0.f;
                    Cs[(mh * 16 + q * 4 + i) * 136 + j * 16 + l16] = f2bf(v);
                }
        // same-wave ds_write->ds_read ordered via lgkmcnt. 512 chunks of 8.
#pragma unroll
        for (int jj = 0; jj < 8; jj++) {
            int f = jj * 64 + l;
            int r = f >> 4, cc = (f & 15) * 8;
            uint4 cv = *(const uint4*)&Cs[r * 136 + cc];
            int row = m0 + r;
            if (row < NN) *(uint4*)(outb + (size_t)row * ldob + n0 + cc) = cv;
        }
        return;
    }

    // ---- mode 2: fused classifier ----
    // h3 (relu, bf16) -> shared LDS [32][264] row-major
    u16* Csh = lds + 4096;
#pragma unroll
    for (int mh = 0; mh < 2; mh++)
#pragma unroll
        for (int j = 0; j < 8; j++)
#pragma unroll
            for (int i = 0; i < 4; i++) {
                float v = acc[mh][j][i];
                v = v > 0.f ? v : 0.f;
                Csh[(mh * 16 + q * 4 + i) * 264 + n0 + j * 16 + l16] = f2bf(v);
            }
    __syncthreads();  // h3 visible to both waves

#pragma unroll
    for (int mh = 0; mh < 2; mh++)
#pragma unroll
        for (int j = 0; j < 8; j++)
            acc[mh][j] = (f32x4){0.f, 0.f, 0.f, 0.f};

    // phase B: z = [jk0,jk1,jk2,h3] @ w1T (K=1024, 32 steps)
    const u16* bfw2 = Bf2 + (size_t)(wv * 8) * 512 + l * 8;
    auto loadB2 = [&](bf16x8* dst, int s) {
#pragma unroll
        for (int j = 0; j < 8; j++)
            dst[j] = *(const bf16x8*)(bfw2 + (size_t)s * 8192 + j * 512);
    };
    auto stageB = [&](int buf, int s) {
        int kt = s * 32;
        const u16* ap = jkb + (size_t)(kt >> 8) * 256;
        gll16(ap + (size_t)arow * 1024 + (kt & 255) + q * 8, lds + buf * 1024 + wv * 512);
    };
    auto comph = [&](int ss, const bf16x8* b) {
        bf16x8 a[2];
#pragma unroll
        for (int mh = 0; mh < 2; mh++)
            a[mh] = *(const bf16x8*)(Csh + (mh * 16 + l16) * 264 + ss * 32 + q * 8);
#pragma unroll
        for (int mh = 0; mh < 2; mh++)
#pragma unroll
            for (int j = 0; j < 8; j++)
                acc[mh][j] =
                    __builtin_amdgcn_mfma_f32_16x16x32_bf16(a[mh], b[j], acc[mh][j], 0, 0, 0);
    };

    loadB2(bA, 0);
    stageB(0, 0);
    stageB(1, 1);
    stageB(2, 2);
    for (int s = 0; s < 24; s += 2) {
        if (s == 0)               asm volatile("s_waitcnt vmcnt(2)" ::: "memory");
        else                      asm volatile("s_waitcnt vmcnt(10)" ::: "memory");
        __builtin_amdgcn_s_barrier();
        __builtin_amdgcn_sched_barrier(0);
        loadB2(bB, s + 1);
        __builtin_amdgcn_sched_barrier(0);
        if (s + 3 < 24) stageB((s + 3) & 3, s + 3);
        __builtin_amdgcn_sched_barrier(0);
        comp(s & 3, bA);
        asm volatile("s_waitcnt vmcnt(10)" ::: "memory");
        __builtin_amdgcn_s_barrier();
        __builtin_amdgcn_sched_barrier(0);
        loadB2(bA, s + 2);  // s+2 <= 24 < 32 always valid
        __builtin_amdgcn_sched_barrier(0);
        if (s + 4 < 24) stageB((s + 4) & 3, s + 4);
        __builtin_amdgcn_sched_barrier(0);
        comp((s + 1) & 3, bB);
    }
    // h3 steps: no barriers, no manual waits (h3 LDS is read-only now;
    // B regs auto-waited; A-bufs untouched).
    for (int s = 24; s < 32; s += 2) {
        loadB2(bB, s + 1);
        comph(s - 24, bA);
        if (s + 2 < 32) loadB2(bA, s + 2);
        comph(s - 23, bB);
    }

    // classifier epilogue: +b1, relu, BN affine, @w2 + b2 -> logits
    {
        float bi[8], s4[8], h4[8], wa[8], wb[8];
#pragma unroll
        for (int j = 0; j < 8; j++) {
            int col = n0 + j * 16 + l16;
            bi[j] = bias[col];
            s4[j] = sc[col];
            h4[j] = sh[col];
            wa[j] = w2[2 * col];
            wb[j] = w2[2 * col + 1];
        }
        float* red = (float*)lds;  // A-buf area (512 B used)
#pragma unroll
        for (int mh = 0; mh < 2; mh++)
#pragma unroll
            for (int i = 0; i < 4; i++) {
                float p0 = 0.f, p1 = 0.f;
#pragma unroll
                for (int j = 0; j < 8; j++) {
                    float v = acc[mh][j][i] + bi[j];
                    v = v > 0.f ? v : 0.f;
                    v = v * s4[j] + h4[j];
                    p0 += v * wa[j];
                    p1 += v * wb[j];
                }
#pragma unroll
                for (int off = 1; off < 16; off <<= 1) {
                    p0 += __shfl_xor(p0, off, 64);
                    p1 += __shfl_xor(p1, off, 64);
                }
                if (l16 == 0) {
                    int rl = mh * 16 + q * 4 + i;
                    red[(wv * 32 + rl) * 2 + 0] = p0;
                    red[(wv * 32 + rl) * 2 + 1] = p1;
                }
            }
        __syncthreads();
        if (t < 64) {
            int rl = t >> 1, cp = t & 1;
            float v = red[(0 * 32 + rl) * 2 + cp] + red[(1 * 32 + rl) * 2 + cp];
            int row = m0 + rl;
            if (row < NN) outlog[(size_t)row * 2 + cp] = v + b2[cp];
        }
    }
}

extern "C" void kernel_launch(void* const* d_in, const int* in_sizes, int n_in,
                              void* d_out, int out_size, void* d_ws, size_t ws_size,
                              hipStream_t stream) {
    const float* features = (const float*)d_in[0];
    const int* ei = (const int*)d_in[1];
    // d_in[2] = edgenet_input (bypassed by edge_weight_override)
    const float* ew = (const float*)d_in[3];
    const float* cheb_w = (const float*)d_in[4];
    const float* w1 = (const float*)d_in[5];
    const float* b1 = (const float*)d_in[6];
    const float* g = (const float*)d_in[7];
    const float* be = (const float*)d_in[8];
    const float* mn = (const float*)d_in[9];
    const float* vr = (const float*)d_in[10];
    const float* w2 = (const float*)d_in[11];
    const float* b2 = (const float*)d_in[12];
    float* out = (float*)d_out;  // [NN*2] logits, then [EE] ew

    char* p = (char*)d_ws;
    auto alloc = [&](size_t bytes) -> char* {
        char* r = p;
        p += (bytes + 255) & ~(size_t)255;
        return r;
    };
    float* deg = (float*)alloc((size_t)NN * 4);
    int* counts = (int*)alloc((size_t)(NN + 1) * 4);
    int* cursor = (int*)alloc((size_t)NN * 4);
    size_t zero_bytes = (size_t)(p - (char*)deg);
    int* offs = (int*)alloc((size_t)(NN + 1) * 4);
    int2* nbrs = (int2*)alloc((size_t)(EE + 16) * 8);
    u16* xb = (u16*)alloc((size_t)NN * 256 * 2);
    u16* tx1 = (u16*)alloc((size_t)NN * 256 * 2);
    u16* tx2 = (u16*)alloc((size_t)NN * 256 * 2);
    u16* jk = (u16*)alloc((size_t)NN * 1024 * 2);
    u16* chebT = (u16*)alloc((size_t)LGN * 3 * 256 * 256 * 2);  // per layer frag-tiled
    u16* w1T = (u16*)alloc((size_t)1024 * 256 * 2);             // frag-tiled
    float* sc = (float*)alloc(256 * 4);
    float* sh = (float*)alloc(256 * 4);

    hipMemsetAsync(deg, 0, zero_bytes, stream);
    hipMemsetAsync(nbrs + EE, 0, 16 * sizeof(int2), stream);  // safe overrun pad
    k_edge1<<<(EE + 255) / 256, 256, 0, stream>>>(ei, ew, deg, counts, out + (size_t)NN * 2);
    k_scan<<<1, 1024, 0, stream>>>(counts, offs);
    k_scatter<<<(EE + 255) / 256, 256, 0, stream>>>(ei, ew, deg, offs, cursor, nbrs);
    k_cast<<<((NN * 256) + 255) / 256, 256, 0, stream>>>(features, xb, NN * 256);
    k_castB<<<dim3(96, LGN), 256, 0, stream>>>(cheb_w, chebT, 768);
    k_castB<<<dim3(128, 1), 256, 0, stream>>>(w1, w1T, 1024);
    k_foldbn<<<1, 256, 0, stream>>>(g, be, mn, vr, sc, sh);

    const int gg = (NN + 31) / 32;  // 625 blocks (tile M=32 x N=256, 128 thr)
    for (int i = 0; i < LGN; i++) {
        const u16* x = (i == 0) ? xb : (jk + (size_t)(i - 1) * 256);
        int ldx = (i == 0) ? 256 : 1024;
        k_prop<<<NN / 4, 256, 0, stream>>>(x, ldx, (const u16*)nullptr, 0, 0, tx1, 256, offs,
                                           nbrs);
        k_prop<<<NN / 4, 256, 0, stream>>>(tx1, 256, x, ldx, 1, tx2, 256, offs, nbrs);
        if (i < LGN - 1) {
            k_gemm<<<gg, 128, 0, stream>>>(
                x, tx1, tx2, ldx, 256, 256, 768, chebT + (size_t)i * 256 * 768,
                (const u16*)nullptr, (const u16*)nullptr, 0, jk + (size_t)i * 256, 1024,
                (const float*)nullptr, (const float*)nullptr, (const float*)nullptr,
                (const float*)nullptr, (const float*)nullptr, (float*)nullptr);
        } else {
            // fused layer-3 cheb gemm + classifier (mode 2)
            k_gemm<<<gg, 128, 0, stream>>>(
                x, tx1, tx2, ldx, 256, 256, 768, chebT + (size_t)i * 256 * 768,
                w1T, jk, 2, (u16*)nullptr, 0, b1, sc, sh, w2, b2, out);
        }
    }
}

// Round 11
// 439.349 us; speedup vs baseline: 1.2045x; 1.0113x over previous
//
#include <hip/hip_runtime.h>
#include <hip/hip_bf16.h>

#define NN 20000
#define EE 320000
#define LGN 4

typedef unsigned short u16;
typedef short bf16x8 __attribute__((ext_vector_type(8)));
typedef float f32x4 __attribute__((ext_vector_type(4)));

__device__ __forceinline__ float bf2f(u16 v) {
    unsigned int u = ((unsigned int)v) << 16;
    float f; __builtin_memcpy(&f, &u, 4); return f;
}
__device__ __forceinline__ u16 f2bf(float f) {
    __hip_bfloat16 h = __float2bfloat16(f);
    u16 u; __builtin_memcpy(&u, &h, 2); return u;
}

// async global->LDS, 16B per lane, LDS dest = wave-uniform base + lane*16
__device__ __forceinline__ void gll16(const void* g, void* l) {
    __builtin_amdgcn_global_load_lds(
        (const __attribute__((address_space(1))) unsigned int*)g,
        (__attribute__((address_space(3))) unsigned int*)l, 16, 0, 0);
}

// ---- pass 1: degree (by source), col histogram, ew copy-out, pad-zero ----
__global__ __launch_bounds__(256) void k_edge1(const int* __restrict__ ei,
                                               const float* __restrict__ ew,
                                               float* __restrict__ deg,
                                               int* __restrict__ counts,
                                               float* __restrict__ out_ew,
                                               int2* __restrict__ nbrs) {
    int e = blockIdx.x * 256 + threadIdx.x;
    if (blockIdx.x == 0 && threadIdx.x < 16)
        nbrs[EE + threadIdx.x] = make_int2(0, 0);  // gather-overrun pad (read by k_prop)
    if (e >= EE) return;
    int r = ei[e];
    float w = ew[e];
    atomicAdd(&deg[r], w);
    atomicAdd(&counts[ei[EE + e]], 1);
    out_ew[e] = w;
}

// ---- exclusive scan of col histogram (single block) ----
__global__ __launch_bounds__(1024) void k_scan(const int* __restrict__ counts,
                                               int* __restrict__ offs) {
    __shared__ int part[1024];
    int t = threadIdx.x;
    const int C = (NN + 1023) / 1024;  // 20
    int lo = t * C, hi = min(lo + C, NN);
    int s = 0;
    for (int i = lo; i < hi; i++) s += counts[i];
    part[t] = s;
    __syncthreads();
    for (int off = 1; off < 1024; off <<= 1) {
        int add = (t >= off) ? part[t - off] : 0;
        __syncthreads();
        part[t] += add;
        __syncthreads();
    }
    int base = part[t] - s;
    for (int i = lo; i < hi; i++) { offs[i] = base; base += counts[i]; }
    if (t == 1023) offs[NN] = part[1023];
}

// ---- pass 2: compute norm (rsqrt folded in), scatter into CSR slots ----
__global__ __launch_bounds__(256) void k_scatter(const int* __restrict__ ei,
                                                 const float* __restrict__ ew,
                                                 const float* __restrict__ deg,
                                                 const int* __restrict__ offs,
                                                 int* __restrict__ cursor,
                                                 int2* __restrict__ nbrs) {
    int e = blockIdx.x * 256 + threadIdx.x;
    if (e >= EE) return;
    int r = ei[e], c = ei[EE + e];
    float dr = deg[r], dc = deg[c];
    float ir = (dr > 0.f) ? rsqrtf(dr) : 0.f;
    float ic = (dc > 0.f) ? rsqrtf(dc) : 0.f;
    float nm = -(ir * ew[e] * ic);
    int pidx = offs[c] + atomicAdd(&cursor[c], 1);
    nbrs[pidx] = make_int2(r, __float_as_int(nm));
}

// ---- fragment-tile helper: one 16B chunk of Bf layout from f32 [K][256] ----
// chunk u of (K>>5)*1024: lane l=u&63, n-frag f=(u>>6)&15, k-step s=u>>10;
// holds B[col=f*16+(l&15)][k=s*32+(l>>4)*8 .. +7].
__device__ __forceinline__ void castB_chunk(const float* __restrict__ src,
                                            u16* __restrict__ dst, int u) {
    int l = u & 63, f = (u >> 6) & 15, s = u >> 10;
    int col = f * 16 + (l & 15);
    int kb = s * 32 + ((l >> 4) << 3);
    u16 tmp[8];
#pragma unroll
    for (int j = 0; j < 8; j++) tmp[j] = f2bf(src[(size_t)(kb + j) * 256 + col]);
    *(uint4*)(dst + (size_t)u * 8) = *(uint4*)tmp;
}

// ---- R20: fused prep — features cast + chebT castB x4 + w1T castB + foldbn.
// All four jobs are independent; one grid-strided dispatch replaces 4
// (dependent-chain boundary ~3-7 us each, per R10's fused-gemm datum).
// Ranges: [0,5.12M) cast; [.., +98304) chebT (4 sets x 24576, K=768);
// [.., +32768) w1T (K=1024); [.., +256) foldbn.
__global__ __launch_bounds__(256) void k_prep(
    const float* __restrict__ features, u16* __restrict__ xb,
    const float* __restrict__ cheb_w, u16* __restrict__ chebT,
    const float* __restrict__ w1, u16* __restrict__ w1T,
    const float* __restrict__ g, const float* __restrict__ be,
    const float* __restrict__ mn, const float* __restrict__ vr,
    float* __restrict__ sc, float* __restrict__ sh) {
    int tid = blockIdx.x * 256 + threadIdx.x;
    if (tid < NN * 256) {
        xb[tid] = f2bf(features[tid]);
        return;
    }
    tid -= NN * 256;
    if (tid < 4 * 24576) {  // chebT: 4 weight sets, K=768 -> 24576 chunks each
        int set = tid / 24576, u = tid - set * 24576;
        castB_chunk(cheb_w + (size_t)set * 768 * 256, chebT + (size_t)set * 768 * 256, u);
        return;
    }
    tid -= 4 * 24576;
    if (tid < 32768) {  // w1T: K=1024 -> 32768 chunks
        castB_chunk(w1, w1T, tid);
        return;
    }
    tid -= 32768;
    if (tid < 256) {  // fold BN affine
        float s = g[tid] * rsqrtf(vr[tid] + 1e-5f);
        sc[tid] = s;
        sh[tid] = be[tid] - mn[tid] * s;
    }
}

// ---- CSR SpMM: one WAVE per node (R18 ceil-4 form, kept) ----
__global__ __launch_bounds__(256) void k_prop(const u16* __restrict__ x, int ldx,
                                              const u16* __restrict__ xsub, int ldsub,
                                              int dotx2,
                                              u16* __restrict__ out, int ldo,
                                              const int* __restrict__ offs,
                                              const int2* __restrict__ nbrs) {
    int c = __builtin_amdgcn_readfirstlane(blockIdx.x * 4 + (threadIdx.x >> 6));
    int lane = threadIdx.x & 63;
    int s = offs[c], e = offs[c + 1];
    float a0 = 0.f, a1 = 0.f, a2 = 0.f, a3 = 0.f;
    for (int i = s; i < e; i += 16) {
        int2 mm[16];
        ushort4 xv[16];
        bool g1 = (i + 4 < e), g2 = (i + 8 < e), g3 = (i + 12 < e);  // wave-uniform
#pragma unroll
        for (int j = 0; j < 4; j++) mm[j] = nbrs[i + j];
        if (g1) {
#pragma unroll
            for (int j = 4; j < 8; j++) mm[j] = nbrs[i + j];
        }
        if (g2) {
#pragma unroll
            for (int j = 8; j < 12; j++) mm[j] = nbrs[i + j];
        }
        if (g3) {
#pragma unroll
            for (int j = 12; j < 16; j++) mm[j] = nbrs[i + j];
        }
#pragma unroll
        for (int j = 0; j < 4; j++)
            xv[j] = *(const ushort4*)(x + (size_t)mm[j].x * ldx + lane * 4);
        if (g1) {
#pragma unroll
            for (int j = 4; j < 8; j++)
                xv[j] = *(const ushort4*)(x + (size_t)mm[j].x * ldx + lane * 4);
        }
        if (g2) {
#pragma unroll
            for (int j = 8; j < 12; j++)
                xv[j] = *(const ushort4*)(x + (size_t)mm[j].x * ldx + lane * 4);
        }
        if (g3) {
#pragma unroll
            for (int j = 12; j < 16; j++)
                xv[j] = *(const ushort4*)(x + (size_t)mm[j].x * ldx + lane * 4);
        }
#pragma unroll
        for (int j = 0; j < 4; j++) {
            float w = (i + j < e) ? __int_as_float(mm[j].y) : 0.f;
            a0 += w * bf2f(xv[j].x);
            a1 += w * bf2f(xv[j].y);
            a2 += w * bf2f(xv[j].z);
            a3 += w * bf2f(xv[j].w);
        }
        if (g1) {
#pragma unroll
            for (int j = 4; j < 8; j++) {
                float w = (i + j < e) ? __int_as_float(mm[j].y) : 0.f;
                a0 += w * bf2f(xv[j].x);
                a1 += w * bf2f(xv[j].y);
                a2 += w * bf2f(xv[j].z);
                a3 += w * bf2f(xv[j].w);
            }
        }
        if (g2) {
#pragma unroll
            for (int j = 8; j < 12; j++) {
                float w = (i + j < e) ? __int_as_float(mm[j].y) : 0.f;
                a0 += w * bf2f(xv[j].x);
                a1 += w * bf2f(xv[j].y);
                a2 += w * bf2f(xv[j].z);
                a3 += w * bf2f(xv[j].w);
            }
        }
        if (g3) {
#pragma unroll
            for (int j = 12; j < 16; j++) {
                float w = (i + j < e) ? __int_as_float(mm[j].y) : 0.f;
                a0 += w * bf2f(xv[j].x);
                a1 += w * bf2f(xv[j].y);
                a2 += w * bf2f(xv[j].z);
                a3 += w * bf2f(xv[j].w);
            }
        }
    }
    if (dotx2) {
        ushort4 xs = *(const ushort4*)(xsub + (size_t)c * ldsub + lane * 4);
        a0 = 2.f * a0 - bf2f(xs.x);
        a1 = 2.f * a1 - bf2f(xs.y);
        a2 = 2.f * a2 - bf2f(xs.z);
        a3 = 2.f * a3 - bf2f(xs.w);
    }
    ushort4 o;
    o.x = f2bf(a0); o.y = f2bf(a1); o.z = f2bf(a2); o.w = f2bf(a3);
    *(ushort4*)(out + (size_t)c * ldo + lane * 4) = o;
}

// ---- bf16 MFMA GEMM, R19 form (unchanged from R10 PASS) ----
// mode 0: cheb-layer gemm, relu -> bf16 jk slice. mode 2: fused layer-3 +
// classifier (h3 kept on-chip in LDS [32][264], then K=1024 contraction:
// jk slices 0-2 streamed + h3 from LDS, then BN/w2 epilogue -> logits).
__global__ __launch_bounds__(128, 2) void k_gemm(
    const u16* __restrict__ A0, const u16* __restrict__ A1,
    const u16* __restrict__ A2,
    int lda0, int lda1, int lda2,
    int K, const u16* __restrict__ Bf, const u16* __restrict__ Bf2,
    const u16* __restrict__ jkb,
    int mode,
    u16* __restrict__ outb, int ldob,
    const float* __restrict__ bias, const float* __restrict__ sc,
    const float* __restrict__ sh,
    const float* __restrict__ w2, const float* __restrict__ b2,
    float* __restrict__ outlog) {
    // [0,4096): 4 A-bufs x 2KB. [4096,12544): h3 [32][264] (mode 2) or
    // mode-0 epilogue Cs (2 waves x 4352 at offset wv*4352, fits 8704).
    __shared__ __align__(16) u16 lds[12544];  // 25088 B
    int t = threadIdx.x;
    int wv = t >> 6, l = t & 63;
    int q = l >> 4, l16 = l & 15;
    int m0 = blockIdx.x * 32;
    int n0 = wv * 128;
    const int steps = K >> 5;  // 24

    f32x4 acc[2][8] = {};  // [mh][nt]

    int arow = m0 + wv * 16 + l16;  // NN = 625*32 exactly; no clamp needed

    auto stageA = [&](int buf, int s) {
        int kt = s * 32;
        int ch = kt >> 8;  // wave-uniform -> SGPR select
        const u16* ap;
        int la;
        if (ch == 0) { ap = A0; la = lda0; }
        else if (ch == 1) { ap = A1; la = lda1; }
        else { ap = A2; la = lda2; }
        gll16(ap + (size_t)arow * la + (kt & 255) + q * 8, lds + buf * 1024 + wv * 512);
    };

    const u16* bfw = Bf + (size_t)(wv * 8) * 512 + l * 8;  // wave frag base + lane
    auto loadB = [&](bf16x8* dst, int s) {
#pragma unroll
        for (int j = 0; j < 8; j++)
            dst[j] = *(const bf16x8*)(bfw + (size_t)s * 8192 + j * 512);
    };
    auto comp = [&](int buf, const bf16x8* b) {
        const u16* base = lds + buf * 1024;
        bf16x8 a[2];
#pragma unroll
        for (int mh = 0; mh < 2; mh++)
            a[mh] = *(const bf16x8*)(base + mh * 512 + l * 8);
#pragma unroll
        for (int mh = 0; mh < 2; mh++)
#pragma unroll
            for (int j = 0; j < 8; j++)
                acc[mh][j] =
                    __builtin_amdgcn_mfma_f32_16x16x32_bf16(a[mh], b[j], acc[mh][j], 0, 0, 0);
    };

    bf16x8 bA[8], bB[8];
    loadB(bA, 0);            // B(0) first: A queue stays behind it
    stageA(0, 0);
    stageA(1, 1);
    stageA(2, 2);
    for (int s = 0; s < steps; s += 2) {
        if (s == 0)               asm volatile("s_waitcnt vmcnt(2)" ::: "memory");
        else                      asm volatile("s_waitcnt vmcnt(10)" ::: "memory");
        __builtin_amdgcn_s_barrier();
        __builtin_amdgcn_sched_barrier(0);
        loadB(bB, s + 1);
        __builtin_amdgcn_sched_barrier(0);
        if (s + 3 < steps) stageA((s + 3) & 3, s + 3);
        __builtin_amdgcn_sched_barrier(0);
        comp(s & 3, bA);
        asm volatile("s_waitcnt vmcnt(10)" ::: "memory");
        __builtin_amdgcn_s_barrier();
        __builtin_amdgcn_sched_barrier(0);
        if (s + 2 < steps) loadB(bA, s + 2);
        __builtin_amdgcn_sched_barrier(0);
        if (s + 4 < steps) stageA((s + 4) & 3, s + 4);
        __builtin_amdgcn_sched_barrier(0);
        comp((s + 1) & 3, bB);
    }
    __syncthreads();  // all waves done with K-loop LDS; reuse below

    if (mode == 0) {
        u16* Cs = lds + 4096 + wv * 4352;  // per-wave [32][136] u16
#pragma unroll
        for (int mh = 0; mh < 2; mh++)
#pragma unroll
            for (int j = 0; j < 8; j++)
#pragma unroll
                for (int i = 0; i < 4; i++) {
                    float v = acc[mh][j][i];
                    v = v > 0.f ? v : 0.f;
                    Cs[(mh * 16 + q * 4 + i) * 136 + j * 16 + l16] = f2bf(v);
                }
        // same-wave ds_write->ds_read ordered via lgkmcnt. 512 chunks of 8.
#pragma unroll
        for (int jj = 0; jj < 8; jj++) {
            int f = jj * 64 + l;
            int r = f >> 4, cc = (f & 15) * 8;
            uint4 cv = *(const uint4*)&Cs[r * 136 + cc];
            int row = m0 + r;
            if (row < NN) *(uint4*)(outb + (size_t)row * ldob + n0 + cc) = cv;
        }
        return;
    }

    // ---- mode 2: fused classifier ----
    // h3 (relu, bf16) -> shared LDS [32][264] row-major
    u16* Csh = lds + 4096;
#pragma unroll
    for (int mh = 0; mh < 2; mh++)
#pragma unroll
        for (int j = 0; j < 8; j++)
#pragma unroll
            for (int i = 0; i < 4; i++) {
                float v = acc[mh][j][i];
                v = v > 0.f ? v : 0.f;
                Csh[(mh * 16 + q * 4 + i) * 264 + n0 + j * 16 + l16] = f2bf(v);
            }
    __syncthreads();  // h3 visible to both waves

#pragma unroll
    for (int mh = 0; mh < 2; mh++)
#pragma unroll
        for (int j = 0; j < 8; j++)
            acc[mh][j] = (f32x4){0.f, 0.f, 0.f, 0.f};

    // phase B: z = [jk0,jk1,jk2,h3] @ w1T (K=1024, 32 steps)
    const u16* bfw2 = Bf2 + (size_t)(wv * 8) * 512 + l * 8;
    auto loadB2 = [&](bf16x8* dst, int s) {
#pragma unroll
        for (int j = 0; j < 8; j++)
            dst[j] = *(const bf16x8*)(bfw2 + (size_t)s * 8192 + j * 512);
    };
    auto stageB = [&](int buf, int s) {
        int kt = s * 32;
        const u16* ap = jkb + (size_t)(kt >> 8) * 256;
        gll16(ap + (size_t)arow * 1024 + (kt & 255) + q * 8, lds + buf * 1024 + wv * 512);
    };
    auto comph = [&](int ss, const bf16x8* b) {
        bf16x8 a[2];
#pragma unroll
        for (int mh = 0; mh < 2; mh++)
            a[mh] = *(const bf16x8*)(Csh + (mh * 16 + l16) * 264 + ss * 32 + q * 8);
#pragma unroll
        for (int mh = 0; mh < 2; mh++)
#pragma unroll
            for (int j = 0; j < 8; j++)
                acc[mh][j] =
                    __builtin_amdgcn_mfma_f32_16x16x32_bf16(a[mh], b[j], acc[mh][j], 0, 0, 0);
    };

    loadB2(bA, 0);
    stageB(0, 0);
    stageB(1, 1);
    stageB(2, 2);
    for (int s = 0; s < 24; s += 2) {
        if (s == 0)               asm volatile("s_waitcnt vmcnt(2)" ::: "memory");
        else                      asm volatile("s_waitcnt vmcnt(10)" ::: "memory");
        __builtin_amdgcn_s_barrier();
        __builtin_amdgcn_sched_barrier(0);
        loadB2(bB, s + 1);
        __builtin_amdgcn_sched_barrier(0);
        if (s + 3 < 24) stageB((s + 3) & 3, s + 3);
        __builtin_amdgcn_sched_barrier(0);
        comp(s & 3, bA);
        asm volatile("s_waitcnt vmcnt(10)" ::: "memory");
        __builtin_amdgcn_s_barrier();
        __builtin_amdgcn_sched_barrier(0);
        loadB2(bA, s + 2);  // s+2 <= 24 < 32 always valid
        __builtin_amdgcn_sched_barrier(0);
        if (s + 4 < 24) stageB((s + 4) & 3, s + 4);
        __builtin_amdgcn_sched_barrier(0);
        comp((s + 1) & 3, bB);
    }
    // h3 steps: no barriers, no manual waits (h3 LDS is read-only now;
    // B regs auto-waited; A-bufs untouched).
    for (int s = 24; s < 32; s += 2) {
        loadB2(bB, s + 1);
        comph(s - 24, bA);
        if (s + 2 < 32) loadB2(bA, s + 2);
        comph(s - 23, bB);
    }

    // classifier epilogue: +b1, relu, BN affine, @w2 + b2 -> logits
    {
        float bi[8], s4[8], h4[8], wa[8], wb[8];
#pragma unroll
        for (int j = 0; j < 8; j++) {
            int col = n0 + j * 16 + l16;
            bi[j] = bias[col];
            s4[j] = sc[col];
            h4[j] = sh[col];
            wa[j] = w2[2 * col];
            wb[j] = w2[2 * col + 1];
        }
        float* red = (float*)lds;  // A-buf area (512 B used)
#pragma unroll
        for (int mh = 0; mh < 2; mh++)
#pragma unroll
            for (int i = 0; i < 4; i++) {
                float p0 = 0.f, p1 = 0.f;
#pragma unroll
                for (int j = 0; j < 8; j++) {
                    float v = acc[mh][j][i] + bi[j];
                    v = v > 0.f ? v : 0.f;
                    v = v * s4[j] + h4[j];
                    p0 += v * wa[j];
                    p1 += v * wb[j];
                }
#pragma unroll
                for (int off = 1; off < 16; off <<= 1) {
                    p0 += __shfl_xor(p0, off, 64);
                    p1 += __shfl_xor(p1, off, 64);
                }
                if (l16 == 0) {
                    int rl = mh * 16 + q * 4 + i;
                    red[(wv * 32 + rl) * 2 + 0] = p0;
                    red[(wv * 32 + rl) * 2 + 1] = p1;
                }
            }
        __syncthreads();
        if (t < 64) {
            int rl = t >> 1, cp = t & 1;
            float v = red[(0 * 32 + rl) * 2 + cp] + red[(1 * 32 + rl) * 2 + cp];
            int row = m0 + rl;
            if (row < NN) outlog[(size_t)row * 2 + cp] = v + b2[cp];
        }
    }
}

extern "C" void kernel_launch(void* const* d_in, const int* in_sizes, int n_in,
                              void* d_out, int out_size, void* d_ws, size_t ws_size,
                              hipStream_t stream) {
    const float* features = (const float*)d_in[0];
    const int* ei = (const int*)d_in[1];
    // d_in[2] = edgenet_input (bypassed by edge_weight_override)
    const float* ew = (const float*)d_in[3];
    const float* cheb_w = (const float*)d_in[4];
    const float* w1 = (const float*)d_in[5];
    const float* b1 = (const float*)d_in[6];
    const float* g = (const float*)d_in[7];
    const float* be = (const float*)d_in[8];
    const float* mn = (const float*)d_in[9];
    const float* vr = (const float*)d_in[10];
    const float* w2 = (const float*)d_in[11];
    const float* b2 = (const float*)d_in[12];
    float* out = (float*)d_out;  // [NN*2] logits, then [EE] ew

    char* p = (char*)d_ws;
    auto alloc = [&](size_t bytes) -> char* {
        char* r = p;
        p += (bytes + 255) & ~(size_t)255;
        return r;
    };
    float* deg = (float*)alloc((size_t)NN * 4);
    int* counts = (int*)alloc((size_t)(NN + 1) * 4);
    int* cursor = (int*)alloc((size_t)NN * 4);
    size_t zero_bytes = (size_t)(p - (char*)deg);
    int* offs = (int*)alloc((size_t)(NN + 1) * 4);
    int2* nbrs = (int2*)alloc((size_t)(EE + 16) * 8);
    u16* xb = (u16*)alloc((size_t)NN * 256 * 2);
    u16* tx1 = (u16*)alloc((size_t)NN * 256 * 2);
    u16* tx2 = (u16*)alloc((size_t)NN * 256 * 2);
    u16* jk = (u16*)alloc((size_t)NN * 1024 * 2);
    u16* chebT = (u16*)alloc((size_t)LGN * 3 * 256 * 256 * 2);  // per layer frag-tiled
    u16* w1T = (u16*)alloc((size_t)1024 * 256 * 2);             // frag-tiled
    float* sc = (float*)alloc(256 * 4);
    float* sh = (float*)alloc(256 * 4);

    hipMemsetAsync(deg, 0, zero_bytes, stream);
    k_edge1<<<(EE + 255) / 256, 256, 0, stream>>>(ei, ew, deg, counts, out + (size_t)NN * 2,
                                                  nbrs);
    k_scan<<<1, 1024, 0, stream>>>(counts, offs);
    k_scatter<<<(EE + 255) / 256, 256, 0, stream>>>(ei, ew, deg, offs, cursor, nbrs);
    // fused prep: cast + 5 castB sets + foldbn (5,251,328 work items)
    const int prep_items = NN * 256 + 4 * 24576 + 32768 + 256;
    k_prep<<<(prep_items + 255) / 256, 256, 0, stream>>>(features, xb, cheb_w, chebT, w1, w1T,
                                                         g, be, mn, vr, sc, sh);

    const int gg = (NN + 31) / 32;  // 625 blocks (tile M=32 x N=256, 128 thr)
    for (int i = 0; i < LGN; i++) {
        const u16* x = (i == 0) ? xb : (jk + (size_t)(i - 1) * 256);
        int ldx = (i == 0) ? 256 : 1024;
        k_prop<<<NN / 4, 256, 0, stream>>>(x, ldx, (const u16*)nullptr, 0, 0, tx1, 256, offs,
                                           nbrs);
        k_prop<<<NN / 4, 256, 0, stream>>>(tx1, 256, x, ldx, 1, tx2, 256, offs, nbrs);
        if (i < LGN - 1) {
            k_gemm<<<gg, 128, 0, stream>>>(
                x, tx1, tx2, ldx, 256, 256, 768, chebT + (size_t)i * 256 * 768,
                (const u16*)nullptr, (const u16*)nullptr, 0, jk + (size_t)i * 256, 1024,
                (const float*)nullptr, (const float*)nullptr, (const float*)nullptr,
                (const float*)nullptr, (const float*)nullptr, (float*)nullptr);
        } else {
            // fused layer-3 cheb gemm + classifier (mode 2)
            k_gemm<<<gg, 128, 0, stream>>>(
                x, tx1, tx2, ldx, 256, 256, 768, chebT + (size_t)i * 256 * 768,
                w1T, jk, 2, (u16*)nullptr, 0, b1, sc, sh, w2, b2, out);
        }
    }
}